// Round 2
// baseline (26257.156 us; speedup 1.0000x reference)
//
#include <hip/hip_runtime.h>

#define NEGC (-1e9f)

// ws offsets (floats)
#define OFF_DENSE   0           //  2,097,152  [B*L*D]
#define OFF_ENCOUT  2097152     //  4,194,304  [B*L*H]
#define OFF_ENCKEYS 6291456     //  4,194,304  [B*L*512]
#define OFF_PTRKEYS 10485760    //  2,097,152  [B*L*256]
#define OFF_X       12582912    //     98,304  [B*768]  (ctx|dec_in)
#define OFF_HA      12681216    //     65,536
#define OFF_HB      12746752    //     65,536
#define OFF_H0      12812288    //     65,536
#define OFF_WC      12877824    //    393,216  [512 h][768 o] = [s2s_Wq | W_out^T@ptr_Wq]
#define OFF_BQ      13271040    //        256
#define OFF_QPART   13271296    //  1,572,864  [16 ut][128 b][768 o]
#define OFF_SMASK   14844160    //      8,192 ints
#define OFF_BAR     14852352    //          2 uints
// total ~14,852,354 floats = 59.4 MB

__device__ __forceinline__ float fast_tanh(float x) {
  float e = __expf(2.0f * x);
  return 1.0f - 2.0f / (e + 1.0f);
}
__device__ __forceinline__ float sigmoidf_(float x) {
  return 1.0f / (1.0f + __expf(-x));
}
__device__ __forceinline__ float wsum(float v) {
#pragma unroll
  for (int o = 32; o > 0; o >>= 1) v += __shfl_xor(v, o);
  return v;
}
#define D4(acc) fmaf(xv.x, w.x, fmaf(xv.y, w.y, fmaf(xv.z, w.z, fmaf(xv.w, w.w, acc))))

// ---- device-scope grid barrier (epoch e = 1,2,3,...; cnt monotone) ----
__device__ __forceinline__ void gbar(unsigned* cnt, unsigned* flg, unsigned e) {
  __syncthreads();
  if (threadIdx.x == 0) {
    __threadfence();  // release block's plain stores at agent scope
    unsigned prev = __hip_atomic_fetch_add(cnt, 1u, __ATOMIC_ACQ_REL, __HIP_MEMORY_SCOPE_AGENT);
    if (prev == 256u * e - 1u) {
      __hip_atomic_store(flg, e, __ATOMIC_RELEASE, __HIP_MEMORY_SCOPE_AGENT);
    } else {
      while (__hip_atomic_load(flg, __ATOMIC_ACQUIRE, __HIP_MEMORY_SCOPE_AGENT) < e) {
        __builtin_amdgcn_s_sleep(2);
      }
    }
  }
  __syncthreads();
}

__global__ __launch_bounds__(256)
void k_init2(float* hA, int* smask, unsigned* bar) {
  int idx = blockIdx.x * 256 + threadIdx.x;   // grid 256*256 = 65536
  if (idx < 65536) hA[idx] = 0.f;
  if (idx < 8192) smask[idx] = 1;
  if (idx < 2) bar[idx] = 0;
}

// ---------------- decoder phase 1 (attention + pointer output) ----------------
__device__ __forceinline__ void dec_p1(
    int i, float* sm, int tid, int bid,
    const float* qpart, const float* bq, const float* enc_keys,
    const float* ptr_keys, const float* enc_out, const float* dense,
    const float* sv_g, const float* pv_g, const int* lengths,
    const int* targets, int* smask, float* xbuf, float* logits, float* preds) {
  const int wv = tid >> 6, ln = tid & 63;
  if (bid < 128) {
    if (i < 64) {
      const int b = bid;
      const int lenb = lengths[b];
      {  // reduce q (o<512) over 16 u-tiles
        float s = 0.f;
#pragma unroll
        for (int ut = 0; ut < 16; ++ut) s += qpart[(ut * 128 + b) * 768 + tid];
        sm[tid] = s;            // sq
        sm[512 + tid] = sv_g[tid];  // sv
      }
      __syncthreads();
#pragma unroll
      for (int li = 0; li < 8; ++li) {
        int l = wv * 8 + li;
        float acc = 0.f;
#pragma unroll
        for (int c = 0; c < 8; ++c) {
          int a = c * 64 + ln;
          acc = fmaf(fast_tanh(sm[a] + enc_keys[(b * 64 + l) * 512 + a]), sm[512 + a], acc);
        }
        acc = wsum(acc);
        if (ln == 0) sm[1024 + l] = ((i < lenb) && (l < lenb)) ? acc : NEGC;
      }
      __syncthreads();
      if (tid < 64) {
        float v = sm[1024 + tid];
        float m = v;
#pragma unroll
        for (int off = 32; off > 0; off >>= 1) m = fmaxf(m, __shfl_xor(m, off));
        float e = __expf(v - m);
        float s = e;
#pragma unroll
        for (int off = 32; off > 0; off >>= 1) s += __shfl_xor(s, off);
        sm[1088 + tid] = e / s;
      }
      __syncthreads();
      {
        float c = 0.f;
#pragma unroll 8
        for (int l = 0; l < 64; ++l)
          c = fmaf(sm[1088 + l], enc_out[(b * 64 + l) * 512 + tid], c);
        xbuf[b * 768 + tid] = c;
      }
      if (tid < 256) {
        int idx = (i == 0) ? 0 : targets[b * 64 + i - 1];
        xbuf[b * 768 + 512 + tid] = dense[(b * 64 + idx) * 256 + tid];
      }
    }
  } else {
    if (i >= 1) {
      const int b = bid - 128, j = i - 1;
      const int lenb = lengths[b];
      if (tid < 256) {
        float s = 0.f;
#pragma unroll
        for (int ut = 0; ut < 16; ++ut) s += qpart[(ut * 128 + b) * 768 + 512 + tid];
        sm[tid] = s + bq[tid];      // spq
        sm[512 + tid] = pv_g[tid];  // pv
      }
      __syncthreads();
#pragma unroll
      for (int li = 0; li < 8; ++li) {
        int l = wv * 8 + li;
        float acc = 0.f;
#pragma unroll
        for (int c = 0; c < 4; ++c) {
          int a = c * 64 + ln;
          acc = fmaf(fast_tanh(sm[a] + ptr_keys[(b * 64 + l) * 256 + a]), sm[512 + a], acc);
        }
        acc = wsum(acc);
        if (ln == 0) sm[1024 + l] = acc;
      }
      __syncthreads();
      if (tid < 64) {
        int l = tid;
        bool pm = (j < lenb) && (l < lenb) && (smask[b * 64 + l] != 0);
        float v = pm ? sm[1024 + l] : NEGC;
        logits[(b * 64 + j) * 64 + l] = v;
        float bv = v; int bidx = l;
#pragma unroll
        for (int off = 32; off > 0; off >>= 1) {
          float ov = __shfl_xor(bv, off);
          int oi = __shfl_xor(bidx, off);
          if (ov > bv || (ov == bv && oi < bidx)) { bv = ov; bidx = oi; }
        }
        if (l == 0) preds[b * 64 + j] = (float)bidx;
        if (l == 0) smask[b * 64 + targets[b * 64 + j]] = 0;
      }
    }
  }
}

// ---------------- the persistent kernel ----------------
__global__ __launch_bounds__(512, 2)
void k_persist(const float* __restrict__ inp, const int* __restrict__ lengths,
               const int* __restrict__ targets,
               const float* __restrict__ W_in, const float* __restrict__ b_in,
               const float* __restrict__ eWi, const float* __restrict__ eWh,
               const float* __restrict__ ebi, const float* __restrict__ ebh,
               const float* __restrict__ dWi, const float* __restrict__ dWh,
               const float* __restrict__ dbi, const float* __restrict__ dbh,
               const float* __restrict__ Wq, const float* __restrict__ Wk,
               const float* __restrict__ sv_g,
               const float* __restrict__ W_out, const float* __restrict__ b_out,
               const float* __restrict__ pWq, const float* __restrict__ pWk,
               const float* __restrict__ pv_g,
               float* __restrict__ ws, float* __restrict__ logits,
               float* __restrict__ preds) {
  __shared__ float sm[14400];   // 57.6 KB — sized by encoder phase (12352 xs + 2048 part)
  float* dense    = ws + OFF_DENSE;
  float* enc_out  = ws + OFF_ENCOUT;
  float* enc_keys = ws + OFF_ENCKEYS;
  float* ptr_keys = ws + OFF_PTRKEYS;
  float* xbuf     = ws + OFF_X;
  float* hA       = ws + OFF_HA;
  float* hB       = ws + OFF_HB;
  float* h0v      = ws + OFF_H0;
  float* WC       = ws + OFF_WC;
  float* bq       = ws + OFF_BQ;
  float* qpart    = ws + OFF_QPART;
  int*   smask    = (int*)(ws + OFF_SMASK);
  unsigned* cnt   = (unsigned*)(ws + OFF_BAR);
  unsigned* flg   = cnt + 1;

  const int tid = threadIdx.x, bid = blockIdx.x;
  unsigned ep = 0;

  // ================= P0a: dense_inputs =================
  for (int idx = bid * 8192 + tid; idx < (bid + 1) * 8192; idx += 512) {
    int bl = idx >> 8, d = idx & 255;
    dense[idx] = fmaf(inp[bl * 2], W_in[d * 2],
                 fmaf(inp[bl * 2 + 1], W_in[d * 2 + 1], b_in[d]));
  }
  gbar(cnt, flg, ++ep);

  // ================= P0b: WC, bq, ptr_keys =================
  // WC[:, :512] = s2s_Wq  (copy)
#pragma unroll
  for (int t2 = 0; t2 < 2; ++t2) {
    int idx = bid * 1024 + t2 * 512 + tid;
    int h = idx >> 9, a = idx & 511;
    WC[h * 768 + a] = Wq[idx];
  }
  // WC[:, 512:] = W_out^T @ ptr_Wq
  {
    int j = bid * 512 + tid;
    int h = j >> 8, a = j & 255;
    float acc = 0.f;
    for (int d = 0; d < 256; ++d)
      acc = fmaf(W_out[d * 512 + h], pWq[d * 256 + a], acc);
    WC[h * 768 + 512 + a] = acc;
  }
  if (bid == 0 && tid < 256) {
    float acc = 0.f;
    for (int d = 0; d < 256; ++d) acc = fmaf(b_out[d], pWq[d * 256 + tid], acc);
    bq[tid] = acc;
  }
  // ptr_keys: 32 rows per block
  {
    const int r0 = bid * 32;
    for (int idx = tid; idx < 32 * 256; idx += 512) {
      int r = idx >> 8, d = idx & 255;
      sm[r * 260 + d] = dense[(r0 + r) * 256 + d];
    }
    __syncthreads();
    const int o = tid & 255, rh = tid >> 8;
    float acc[16];
#pragma unroll
    for (int ri = 0; ri < 16; ++ri) acc[ri] = 0.f;
    for (int d = 0; d < 256; ++d) {
      float w = pWk[d * 256 + o];
#pragma unroll
      for (int ri = 0; ri < 16; ++ri)
        acc[ri] = fmaf(sm[(rh * 16 + ri) * 260 + d], w, acc[ri]);
    }
#pragma unroll
    for (int ri = 0; ri < 16; ++ri)
      ptr_keys[(r0 + rh * 16 + ri) * 256 + o] = acc[ri];
  }
  gbar(cnt, flg, ++ep);

  // ================= Encoder: 64 GRU steps =================
  const int bt_e = bid >> 5, ut_e = bid & 31;
  const int b0e = bt_e * 16, u0e = ut_e * 16;
  for (int t = 0; t < 64; ++t) {
    const float* hin = (t & 1) ? hB : hA;
    float* hout      = (t & 1) ? hA : hB;
    for (int idx = tid; idx < 16 * 512; idx += 512) {     // h part
      int bl = idx >> 9, k = idx & 511;
      sm[bl * 772 + k] = hin[(b0e + bl) * 512 + k];
    }
    for (int idx = tid; idx < 16 * 256; idx += 512) {     // dense part
      int bl = idx >> 8, k = idx & 255;
      sm[bl * 772 + 512 + k] = dense[((b0e + bl) * 64 + t) * 256 + k];
    }
    __syncthreads();
    {
      const int b_l = tid & 15, u_l = (tid >> 4) & 15, kp = tid >> 8;
      const int u = u0e + u_l;
      const float* xr = sm + b_l * 772;
      float ar = 0, az = 0, ain = 0, ahn = 0;
      if (kp == 0) {
        const float* wr = eWh + u * 512;
        const float* wz = eWh + (512 + u) * 512;
        const float* wn = eWh + (1024 + u) * 512;
        for (int k = 0; k < 384; k += 4) {
          float4 xv = *(const float4*)(xr + k);
          float4 w;
          w = *(const float4*)(wr + k); ar  = D4(ar);
          w = *(const float4*)(wz + k); az  = D4(az);
          w = *(const float4*)(wn + k); ahn = D4(ahn);
        }
      } else {
        const float* wr = eWh + u * 512;
        const float* wz = eWh + (512 + u) * 512;
        const float* wn = eWh + (1024 + u) * 512;
        for (int k = 384; k < 512; k += 4) {
          float4 xv = *(const float4*)(xr + k);
          float4 w;
          w = *(const float4*)(wr + k); ar  = D4(ar);
          w = *(const float4*)(wz + k); az  = D4(az);
          w = *(const float4*)(wn + k); ahn = D4(ahn);
        }
        const float* vr = eWi + u * 256;
        const float* vz = eWi + (512 + u) * 256;
        const float* vn = eWi + (1024 + u) * 256;
        for (int k = 0; k < 256; k += 4) {
          float4 xv = *(const float4*)(xr + 512 + k);
          float4 w;
          w = *(const float4*)(vr + k); ar  = D4(ar);
          w = *(const float4*)(vz + k); az  = D4(az);
          w = *(const float4*)(vn + k); ain = D4(ain);
        }
      }
      float* pp = sm + 12352 + ((kp * 16 + b_l) * 16 + u_l) * 4;
      pp[0] = ar; pp[1] = az; pp[2] = ain; pp[3] = ahn;
    }
    __syncthreads();
    if (tid < 256) {
      const int b_l = tid & 15, u_l = tid >> 4;
      const float* p0 = sm + 12352 + ((b_l) * 16 + u_l) * 4;
      const float* p1 = sm + 12352 + ((16 + b_l) * 16 + u_l) * 4;
      float ar = p0[0] + p1[0], az = p0[1] + p1[1];
      float ain = p0[2] + p1[2], ahn = p0[3] + p1[3];
      const int u = u0e + u_l, b = b0e + b_l;
      float r = sigmoidf_(ar + ebi[u] + ebh[u]);
      float z = sigmoidf_(az + ebi[512 + u] + ebh[512 + u]);
      float n = fast_tanh(ain + ebi[1024 + u] + r * (ahn + ebh[1024 + u]));
      float hp = sm[b_l * 772 + u];
      float hn = (1.f - z) * n + z * hp;
      hout[b * 512 + u] = hn;
      int lenb = lengths[b];
      enc_out[(b * 64 + t) * 512 + u] = (t < lenb) ? hn : 0.f;
      if (t == lenb - 1) h0v[b * 512 + u] = hn;
    }
    gbar(cnt, flg, ++ep);
  }

  // ================= EK: enc_keys + qpart(h0) =================
  const int bt_d = bid >> 4, ut_d = bid & 15;
  const int b0d = bt_d * 8, u0d = ut_d * 32;
#pragma unroll 1
  for (int pass = 0; pass < 2; ++pass) {
    const int r0 = bid * 32 + pass * 16;
    for (int idx = tid; idx < 16 * 512; idx += 512) {
      int r = idx >> 9, h = idx & 511;
      sm[r * 516 + h] = enc_out[(r0 + r) * 512 + h];
    }
    __syncthreads();
    float acc[16];
#pragma unroll
    for (int ri = 0; ri < 16; ++ri) acc[ri] = 0.f;
    for (int h = 0; h < 512; ++h) {
      float w = Wk[h * 512 + tid];
#pragma unroll
      for (int ri = 0; ri < 16; ++ri) acc[ri] = fmaf(sm[ri * 516 + h], w, acc[ri]);
    }
#pragma unroll
    for (int ri = 0; ri < 16; ++ri) enc_keys[(r0 + ri) * 512 + tid] = acc[ri];
    __syncthreads();
  }
  {  // qpart from h0
    if (tid < 256) sm[tid] = h0v[(b0d + (tid >> 5)) * 512 + u0d + (tid & 31)];
    __syncthreads();
    for (int o = tid; o < 768; o += 512) {
      float acc[8];
#pragma unroll
      for (int b = 0; b < 8; ++b) acc[b] = 0.f;
      for (int k = 0; k < 32; ++k) {
        float w = WC[(u0d + k) * 768 + o];
#pragma unroll
        for (int b = 0; b < 8; ++b) acc[b] = fmaf(sm[b * 32 + k], w, acc[b]);
      }
#pragma unroll
      for (int b = 0; b < 8; ++b) qpart[(ut_d * 128 + b0d + b) * 768 + o] = acc[b];
    }
  }
  gbar(cnt, flg, ++ep);

  // ================= Decoder: 64 steps, 2 barriers each =================
  for (int i = 0; i <= 64; ++i) {
    dec_p1(i, sm, tid, bid, qpart, bq, enc_keys, ptr_keys, enc_out, dense,
           sv_g, pv_g, lengths, targets, smask, xbuf, logits, preds);
    if (i == 64) break;
    gbar(cnt, flg, ++ep);

    // ---- D2: GRU gates GEMM + pointwise + split-K q/pq epilogue ----
    const float* hin = (i == 0) ? h0v : ((i & 1) ? hB : hA);
    float* hout      = (i & 1) ? hA : hB;
    for (int idx = tid; idx < 8 * 768; idx += 512) {
      int bl = idx / 768, k = idx - bl * 768;
      sm[bl * 1284 + k] = xbuf[(b0d + bl) * 768 + k];
    }
    for (int idx = tid; idx < 8 * 512; idx += 512) {
      int bl = idx >> 9, k = idx & 511;
      sm[bl * 1284 + 768 + k] = hin[(b0d + bl) * 512 + k];
    }
    __syncthreads();
    {
      const int b_l = tid & 7, u_l = (tid >> 3) & 31, kp = tid >> 8;
      const int u = u0d + u_l;
      const float* xr = sm + b_l * 1284;
      float ar = 0, az = 0, ain = 0, ahn = 0;
      const float* wr = dWi + u * 768;
      const float* wz = dWi + (512 + u) * 768;
      const float* wn = dWi + (1024 + u) * 768;
      if (kp == 0) {
        for (int k = 0; k < 640; k += 4) {
          float4 xv = *(const float4*)(xr + k);
          float4 w;
          w = *(const float4*)(wr + k); ar  = D4(ar);
          w = *(const float4*)(wz + k); az  = D4(az);
          w = *(const float4*)(wn + k); ain = D4(ain);
        }
      } else {
        for (int k = 640; k < 768; k += 4) {
          float4 xv = *(const float4*)(xr + k);
          float4 w;
          w = *(const float4*)(wr + k); ar  = D4(ar);
          w = *(const float4*)(wz + k); az  = D4(az);
          w = *(const float4*)(wn + k); ain = D4(ain);
        }
        const float* hr = dWh + u * 512;
        const float* hz = dWh + (512 + u) * 512;
        const float* hn_ = dWh + (1024 + u) * 512;
        for (int k = 0; k < 512; k += 4) {
          float4 xv = *(const float4*)(xr + 768 + k);
          float4 w;
          w = *(const float4*)(hr + k);  ar  = D4(ar);
          w = *(const float4*)(hz + k);  az  = D4(az);
          w = *(const float4*)(hn_ + k); ahn = D4(ahn);
        }
      }
      float* pp = sm + 10272 + ((kp * 8 + b_l) * 32 + u_l) * 4;
      pp[0] = ar; pp[1] = az; pp[2] = ain; pp[3] = ahn;
    }
    __syncthreads();
    if (tid < 256) {
      const int b_l = tid & 7, u_l = tid >> 3;
      const float* p0 = sm + 10272 + ((b_l) * 32 + u_l) * 4;
      const float* p1 = sm + 10272 + ((8 + b_l) * 32 + u_l) * 4;
      float ar = p0[0] + p1[0], az = p0[1] + p1[1];
      float ain = p0[2] + p1[2], ahn = p0[3] + p1[3];
      const int u = u0d + u_l, b = b0d + b_l;
      float r = sigmoidf_(ar + dbi[u] + dbh[u]);
      float z = sigmoidf_(az + dbi[512 + u] + dbh[512 + u]);
      float n = fast_tanh(ain + dbi[1024 + u] + r * (ahn + dbh[1024 + u]));
      float hp = sm[b_l * 1284 + 768 + u];
      float hnv = (1.f - z) * n + z * hp;
      hout[b * 512 + u] = hnv;
      sm[12320 + b_l * 32 + u_l] = hnv;   // stash for epilogue
    }
    __syncthreads();
    for (int o = tid; o < 768; o += 512) {
      float acc[8];
#pragma unroll
      for (int b = 0; b < 8; ++b) acc[b] = 0.f;
      for (int k = 0; k < 32; ++k) {
        float w = WC[(u0d + k) * 768 + o];
#pragma unroll
        for (int b = 0; b < 8; ++b) acc[b] = fmaf(sm[12320 + b * 32 + k], w, acc[b]);
      }
#pragma unroll
      for (int b = 0; b < 8; ++b) qpart[(ut_d * 128 + b0d + b) * 768 + o] = acc[b];
    }
    gbar(cnt, flg, ++ep);
  }
}

extern "C" void kernel_launch(void* const* d_in, const int* in_sizes, int n_in,
                              void* d_out, int out_size, void* d_ws, size_t ws_size,
                              hipStream_t stream) {
  (void)in_sizes; (void)n_in; (void)out_size; (void)ws_size;
  const float* inputs  = (const float*)d_in[0];
  const int*   lengths = (const int*)d_in[1];
  const int*   targets = (const int*)d_in[2];
  const float* W_in    = (const float*)d_in[3];
  const float* b_in    = (const float*)d_in[4];
  const float* enc_Wi  = (const float*)d_in[5];
  const float* enc_Wh  = (const float*)d_in[6];
  const float* enc_bi  = (const float*)d_in[7];
  const float* enc_bh  = (const float*)d_in[8];
  const float* dec_Wi  = (const float*)d_in[9];
  const float* dec_Wh  = (const float*)d_in[10];
  const float* dec_bi  = (const float*)d_in[11];
  const float* dec_bh  = (const float*)d_in[12];
  const float* s2s_Wq  = (const float*)d_in[13];
  const float* s2s_Wk  = (const float*)d_in[14];
  const float* s2s_v   = (const float*)d_in[15];
  const float* W_out   = (const float*)d_in[16];
  const float* b_out   = (const float*)d_in[17];
  const float* ptr_Wq  = (const float*)d_in[18];
  const float* ptr_Wk  = (const float*)d_in[19];
  const float* ptr_v   = (const float*)d_in[20];

  float* ws = (float*)d_ws;
  float* logits = (float*)d_out;
  float* preds  = (float*)d_out + 128 * 64 * 64;

  k_init2<<<256, 256, 0, stream>>>(ws + OFF_HA, (int*)(ws + OFF_SMASK),
                                   (unsigned*)(ws + OFF_BAR));
  k_persist<<<256, 512, 0, stream>>>(inputs, lengths, targets, W_in, b_in,
                                     enc_Wi, enc_Wh, enc_bi, enc_bh,
                                     dec_Wi, dec_Wh, dec_bi, dec_bh,
                                     s2s_Wq, s2s_Wk, s2s_v, W_out, b_out,
                                     ptr_Wq, ptr_Wk, ptr_v,
                                     ws, logits, preds);
}

// Round 4
// 16621.153 us; speedup vs baseline: 1.5797x; 1.5797x over previous
//
#include <hip/hip_runtime.h>

#define NEGC (-1e9f)

// ws offsets (floats)
#define OFF_DENSE   0           //  2,097,152  [B*L*D]
#define OFF_ENCOUT  2097152     //  4,194,304  [B*L*H]
#define OFF_ENCKEYS 6291456     //  4,194,304  [B*L*512]
#define OFF_PTRKEYS 10485760    //  2,097,152  [B*L*256]
#define OFF_X       12582912    //     98,304  [B*768]  (ctx|dec_in)
#define OFF_HA      12681216    //     65,536
#define OFF_HB      12746752    //     65,536
#define OFF_H0      12812288    //     65,536
#define OFF_WC      12877824    //    393,216  [512 h][768 o] = [s2s_Wq | W_out^T@ptr_Wq]
#define OFF_BQ      13271040    //        256
#define OFF_QPART   13271296    //  1,572,864  [16 ut][128 b][768 o]
#define OFF_SMASK   14844160    //      8,192 ints
#define OFF_SLOTS   14852352    //      4,096 uints (256 slots, 64B stride)
#define OFF_FLG     14856448    //         16 uints
// total ~14,856,464 floats = 59.4 MB

__device__ __forceinline__ float fast_tanh(float x) {
  float e = __expf(2.0f * x);
  return 1.0f - 2.0f / (e + 1.0f);
}
__device__ __forceinline__ float sigmoidf_(float x) {
  return 1.0f / (1.0f + __expf(-x));
}
__device__ __forceinline__ float wsum(float v) {
#pragma unroll
  for (int o = 32; o > 0; o >>= 1) v += __shfl_xor(v, o);
  return v;
}
#define D4(acc) fmaf(xv.x, w.x, fmaf(xv.y, w.y, fmaf(xv.z, w.z, fmaf(xv.w, w.w, acc))))

// ---- contention-free grid barrier: per-block slots + single aggregator ----
// slots[bid*16] holds last epoch block bid reached (monotone). Block 0 wave 0
// aggregates (4 slots/lane, __all), then releases flg. No atomic RMW anywhere.
// __threadfence() = agent-scope fence on gfx950 (no __hip_atomic_fence builtin).
__device__ __forceinline__ void gbar(unsigned* slots, unsigned* flg, unsigned e) {
  __syncthreads();
  const int tid = threadIdx.x;
  if (blockIdx.x == 0) {
    if (tid < 64) {
      if (tid == 0) {
        __threadfence();
        __hip_atomic_store(slots, e, __ATOMIC_RELAXED, __HIP_MEMORY_SCOPE_AGENT);
      }
      int done;
      do {
        done = 1;
#pragma unroll
        for (int j = 0; j < 4; ++j) {
          unsigned v = __hip_atomic_load(slots + ((tid * 4 + j) << 4),
                                         __ATOMIC_RELAXED, __HIP_MEMORY_SCOPE_AGENT);
          done &= (v >= e);
        }
      } while (!__all(done));
      if (tid == 0)
        __hip_atomic_store(flg, e, __ATOMIC_RELEASE, __HIP_MEMORY_SCOPE_AGENT);
      __threadfence();   // acquire side: discard stale cached lines
    }
  } else {
    if (tid == 0) {
      __threadfence();
      __hip_atomic_store(slots + (blockIdx.x << 4), e, __ATOMIC_RELAXED,
                         __HIP_MEMORY_SCOPE_AGENT);
      while (__hip_atomic_load(flg, __ATOMIC_RELAXED, __HIP_MEMORY_SCOPE_AGENT) < e)
        __builtin_amdgcn_s_sleep(1);
      __threadfence();   // acquire side
    }
  }
  __syncthreads();
}

__global__ __launch_bounds__(256)
void k_init2(float* hA, int* smask, unsigned* slots, unsigned* flg) {
  int idx = blockIdx.x * 256 + threadIdx.x;   // grid 256*256 = 65536
  if (idx < 65536) hA[idx] = 0.f;
  if (idx < 8192) smask[idx] = 1;
  if (idx < 4096) slots[idx] = 0;
  if (idx < 16) flg[idx] = 0;
}

// ---------------- decoder phase 1 (attention + pointer output) ----------------
__device__ __forceinline__ void dec_p1(
    int i, float* sm, int tid, int bid,
    const float* qpart, const float* bq, const float* enc_keys,
    const float* ptr_keys, const float* enc_out, const float* dense,
    const float* sv_g, const float* pv_g, const int* lengths,
    const int* targets, int* smask, float* xbuf, float* logits, float* preds) {
  const int wv = tid >> 6, ln = tid & 63;
  if (bid < 128) {
    if (i < 64) {
      const int b = bid;
      const int lenb = lengths[b];
      {  // reduce q (o<512) over 16 u-tiles
        float s = 0.f;
#pragma unroll
        for (int ut = 0; ut < 16; ++ut) s += qpart[(ut * 128 + b) * 768 + tid];
        sm[tid] = s;            // sq
        sm[512 + tid] = sv_g[tid];  // sv
      }
      __syncthreads();
#pragma unroll
      for (int li = 0; li < 8; ++li) {
        int l = wv * 8 + li;
        float acc = 0.f;
#pragma unroll
        for (int c = 0; c < 8; ++c) {
          int a = c * 64 + ln;
          acc = fmaf(fast_tanh(sm[a] + enc_keys[(b * 64 + l) * 512 + a]), sm[512 + a], acc);
        }
        acc = wsum(acc);
        if (ln == 0) sm[1024 + l] = ((i < lenb) && (l < lenb)) ? acc : NEGC;
      }
      __syncthreads();
      if (tid < 64) {
        float v = sm[1024 + tid];
        float m = v;
#pragma unroll
        for (int off = 32; off > 0; off >>= 1) m = fmaxf(m, __shfl_xor(m, off));
        float e = __expf(v - m);
        float s = e;
#pragma unroll
        for (int off = 32; off > 0; off >>= 1) s += __shfl_xor(s, off);
        sm[1088 + tid] = e / s;
      }
      __syncthreads();
      {
        float c = 0.f;
#pragma unroll 8
        for (int l = 0; l < 64; ++l)
          c = fmaf(sm[1088 + l], enc_out[(b * 64 + l) * 512 + tid], c);
        xbuf[b * 768 + tid] = c;
      }
      if (tid < 256) {
        int idx = (i == 0) ? 0 : targets[b * 64 + i - 1];
        xbuf[b * 768 + 512 + tid] = dense[(b * 64 + idx) * 256 + tid];
      }
    }
  } else {
    if (i >= 1) {
      const int b = bid - 128, j = i - 1;
      const int lenb = lengths[b];
      if (tid < 256) {
        float s = 0.f;
#pragma unroll
        for (int ut = 0; ut < 16; ++ut) s += qpart[(ut * 128 + b) * 768 + 512 + tid];
        sm[tid] = s + bq[tid];      // spq
        sm[512 + tid] = pv_g[tid];  // pv
      }
      __syncthreads();
#pragma unroll
      for (int li = 0; li < 8; ++li) {
        int l = wv * 8 + li;
        float acc = 0.f;
#pragma unroll
        for (int c = 0; c < 4; ++c) {
          int a = c * 64 + ln;
          acc = fmaf(fast_tanh(sm[a] + ptr_keys[(b * 64 + l) * 256 + a]), sm[512 + a], acc);
        }
        acc = wsum(acc);
        if (ln == 0) sm[1024 + l] = acc;
      }
      __syncthreads();
      if (tid < 64) {
        int l = tid;
        bool pm = (j < lenb) && (l < lenb) && (smask[b * 64 + l] != 0);
        float v = pm ? sm[1024 + l] : NEGC;
        logits[(b * 64 + j) * 64 + l] = v;
        float bv = v; int bidx = l;
#pragma unroll
        for (int off = 32; off > 0; off >>= 1) {
          float ov = __shfl_xor(bv, off);
          int oi = __shfl_xor(bidx, off);
          if (ov > bv || (ov == bv && oi < bidx)) { bv = ov; bidx = oi; }
        }
        if (l == 0) preds[b * 64 + j] = (float)bidx;
        if (l == 0) smask[b * 64 + targets[b * 64 + j]] = 0;
      }
    }
  }
}

// ---------------- the persistent kernel ----------------
__global__ __launch_bounds__(512, 2)
void k_persist(const float* __restrict__ inp, const int* __restrict__ lengths,
               const int* __restrict__ targets,
               const float* __restrict__ W_in, const float* __restrict__ b_in,
               const float* __restrict__ eWi, const float* __restrict__ eWh,
               const float* __restrict__ ebi, const float* __restrict__ ebh,
               const float* __restrict__ dWi, const float* __restrict__ dWh,
               const float* __restrict__ dbi, const float* __restrict__ dbh,
               const float* __restrict__ Wq, const float* __restrict__ Wk,
               const float* __restrict__ sv_g,
               const float* __restrict__ W_out, const float* __restrict__ b_out,
               const float* __restrict__ pWq, const float* __restrict__ pWk,
               const float* __restrict__ pv_g,
               float* __restrict__ ws, float* __restrict__ logits,
               float* __restrict__ preds) {
  __shared__ float sm[14400];   // 57.6 KB — sized by encoder phase (12352 xs + 2048 part)
  float* dense    = ws + OFF_DENSE;
  float* enc_out  = ws + OFF_ENCOUT;
  float* enc_keys = ws + OFF_ENCKEYS;
  float* ptr_keys = ws + OFF_PTRKEYS;
  float* xbuf     = ws + OFF_X;
  float* hA       = ws + OFF_HA;
  float* hB       = ws + OFF_HB;
  float* h0v      = ws + OFF_H0;
  float* WC       = ws + OFF_WC;
  float* bq       = ws + OFF_BQ;
  float* qpart    = ws + OFF_QPART;
  int*   smask    = (int*)(ws + OFF_SMASK);
  unsigned* slots = (unsigned*)(ws + OFF_SLOTS);
  unsigned* flg   = (unsigned*)(ws + OFF_FLG);

  const int tid = threadIdx.x, bid = blockIdx.x;
  unsigned ep = 0;

  // XCD-aware tile swizzle: all blocks on one XCD (bid&7) share u-tiles so the
  // per-XCD weight working set (~0.6-1.0 MB) stays L2-resident across steps.
  const int xcd = bid & 7, loc = bid >> 3;
  const int ut_e = (xcd << 2) | (loc & 3), bt_e = loc >> 2;   // enc: 32 ut x 8 bt
  const int ut_d = (xcd << 1) | (loc & 1), bt_d = loc >> 1;   // dec: 16 ut x 16 bt
  const int b0e = bt_e * 16, u0e = ut_e * 16;
  const int b0d = bt_d * 8,  u0d = ut_d * 32;

  // ================= P0a: dense_inputs =================
  for (int idx = bid * 8192 + tid; idx < (bid + 1) * 8192; idx += 512) {
    int bl = idx >> 8, d = idx & 255;
    dense[idx] = fmaf(inp[bl * 2], W_in[d * 2],
                 fmaf(inp[bl * 2 + 1], W_in[d * 2 + 1], b_in[d]));
  }
  gbar(slots, flg, ++ep);

  // ================= P0b: WC, bq, ptr_keys =================
#pragma unroll
  for (int t2 = 0; t2 < 2; ++t2) {
    int idx = bid * 1024 + t2 * 512 + tid;
    int h = idx >> 9, a = idx & 511;
    WC[h * 768 + a] = Wq[idx];
  }
  {
    int j = bid * 512 + tid;
    int h = j >> 8, a = j & 255;
    float acc = 0.f;
    for (int d = 0; d < 256; ++d)
      acc = fmaf(W_out[d * 512 + h], pWq[d * 256 + a], acc);
    WC[h * 768 + 512 + a] = acc;
  }
  if (bid == 0 && tid < 256) {
    float acc = 0.f;
    for (int d = 0; d < 256; ++d) acc = fmaf(b_out[d], pWq[d * 256 + tid], acc);
    bq[tid] = acc;
  }
  {
    const int r0 = bid * 32;
    for (int idx = tid; idx < 32 * 256; idx += 512) {
      int r = idx >> 8, d = idx & 255;
      sm[r * 260 + d] = dense[(r0 + r) * 256 + d];
    }
    __syncthreads();
    const int o = tid & 255, rh = tid >> 8;
    float acc[16];
#pragma unroll
    for (int ri = 0; ri < 16; ++ri) acc[ri] = 0.f;
    for (int d = 0; d < 256; ++d) {
      float w = pWk[d * 256 + o];
#pragma unroll
      for (int ri = 0; ri < 16; ++ri)
        acc[ri] = fmaf(sm[(rh * 16 + ri) * 260 + d], w, acc[ri]);
    }
#pragma unroll
    for (int ri = 0; ri < 16; ++ri)
      ptr_keys[(r0 + rh * 16 + ri) * 256 + o] = acc[ri];
  }
  gbar(slots, flg, ++ep);

  // ================= Encoder: 64 GRU steps =================
  for (int t = 0; t < 64; ++t) {
    const float* hin = (t & 1) ? hB : hA;
    float* hout      = (t & 1) ? hA : hB;
    for (int idx = tid; idx < 16 * 512; idx += 512) {     // h part
      int bl = idx >> 9, k = idx & 511;
      sm[bl * 772 + k] = hin[(b0e + bl) * 512 + k];
    }
    for (int idx = tid; idx < 16 * 256; idx += 512) {     // dense part
      int bl = idx >> 8, k = idx & 255;
      sm[bl * 772 + 512 + k] = dense[((b0e + bl) * 64 + t) * 256 + k];
    }
    __syncthreads();
    {
      const int b_l = tid & 15, u_l = (tid >> 4) & 15, kp = tid >> 8;
      const int u = u0e + u_l;
      const float* xr = sm + b_l * 772;
      float ar = 0, az = 0, ain = 0, ahn = 0;
      if (kp == 0) {
        const float* wr = eWh + u * 512;
        const float* wz = eWh + (512 + u) * 512;
        const float* wn = eWh + (1024 + u) * 512;
        for (int k = 0; k < 384; k += 4) {
          float4 xv = *(const float4*)(xr + k);
          float4 w;
          w = *(const float4*)(wr + k); ar  = D4(ar);
          w = *(const float4*)(wz + k); az  = D4(az);
          w = *(const float4*)(wn + k); ahn = D4(ahn);
        }
      } else {
        const float* wr = eWh + u * 512;
        const float* wz = eWh + (512 + u) * 512;
        const float* wn = eWh + (1024 + u) * 512;
        for (int k = 384; k < 512; k += 4) {
          float4 xv = *(const float4*)(xr + k);
          float4 w;
          w = *(const float4*)(wr + k); ar  = D4(ar);
          w = *(const float4*)(wz + k); az  = D4(az);
          w = *(const float4*)(wn + k); ahn = D4(ahn);
        }
        const float* vr = eWi + u * 256;
        const float* vz = eWi + (512 + u) * 256;
        const float* vn = eWi + (1024 + u) * 256;
        for (int k = 0; k < 256; k += 4) {
          float4 xv = *(const float4*)(xr + 512 + k);
          float4 w;
          w = *(const float4*)(vr + k); ar  = D4(ar);
          w = *(const float4*)(vz + k); az  = D4(az);
          w = *(const float4*)(vn + k); ain = D4(ain);
        }
      }
      float* pp = sm + 12352 + ((kp * 16 + b_l) * 16 + u_l) * 4;
      pp[0] = ar; pp[1] = az; pp[2] = ain; pp[3] = ahn;
    }
    __syncthreads();
    if (tid < 256) {
      const int b_l = tid & 15, u_l = tid >> 4;
      const float* p0 = sm + 12352 + ((b_l) * 16 + u_l) * 4;
      const float* p1 = sm + 12352 + ((16 + b_l) * 16 + u_l) * 4;
      float ar = p0[0] + p1[0], az = p0[1] + p1[1];
      float ain = p0[2] + p1[2], ahn = p0[3] + p1[3];
      const int u = u0e + u_l, b = b0e + b_l;
      float r = sigmoidf_(ar + ebi[u] + ebh[u]);
      float z = sigmoidf_(az + ebi[512 + u] + ebh[512 + u]);
      float n = fast_tanh(ain + ebi[1024 + u] + r * (ahn + ebh[1024 + u]));
      float hp = sm[b_l * 772 + u];
      float hn = (1.f - z) * n + z * hp;
      hout[b * 512 + u] = hn;
      int lenb = lengths[b];
      enc_out[(b * 64 + t) * 512 + u] = (t < lenb) ? hn : 0.f;
      if (t == lenb - 1) h0v[b * 512 + u] = hn;
    }
    gbar(slots, flg, ++ep);
  }

  // ================= EK: enc_keys + qpart(h0) =================
#pragma unroll 1
  for (int pass = 0; pass < 2; ++pass) {
    const int r0 = bid * 32 + pass * 16;
    for (int idx = tid; idx < 16 * 512; idx += 512) {
      int r = idx >> 9, h = idx & 511;
      sm[r * 516 + h] = enc_out[(r0 + r) * 512 + h];
    }
    __syncthreads();
    float acc[16];
#pragma unroll
    for (int ri = 0; ri < 16; ++ri) acc[ri] = 0.f;
    for (int h = 0; h < 512; ++h) {
      float w = Wk[h * 512 + tid];
#pragma unroll
      for (int ri = 0; ri < 16; ++ri) acc[ri] = fmaf(sm[ri * 516 + h], w, acc[ri]);
    }
#pragma unroll
    for (int ri = 0; ri < 16; ++ri) enc_keys[(r0 + ri) * 512 + tid] = acc[ri];
    __syncthreads();
  }
  {  // qpart from h0
    if (tid < 256) sm[tid] = h0v[(b0d + (tid >> 5)) * 512 + u0d + (tid & 31)];
    __syncthreads();
    for (int o = tid; o < 768; o += 512) {
      float acc[8];
#pragma unroll
      for (int b = 0; b < 8; ++b) acc[b] = 0.f;
      for (int k = 0; k < 32; ++k) {
        float w = WC[(u0d + k) * 768 + o];
#pragma unroll
        for (int b = 0; b < 8; ++b) acc[b] = fmaf(sm[b * 32 + k], w, acc[b]);
      }
#pragma unroll
      for (int b = 0; b < 8; ++b) qpart[(ut_d * 128 + b0d + b) * 768 + o] = acc[b];
    }
  }
  gbar(slots, flg, ++ep);

  // ================= Decoder: 64 steps, 2 barriers each =================
  for (int i = 0; i <= 64; ++i) {
    dec_p1(i, sm, tid, bid, qpart, bq, enc_keys, ptr_keys, enc_out, dense,
           sv_g, pv_g, lengths, targets, smask, xbuf, logits, preds);
    if (i == 64) break;
    gbar(slots, flg, ++ep);

    // ---- D2: GRU gates GEMM + pointwise + split-K q/pq epilogue ----
    const float* hin = (i == 0) ? h0v : ((i & 1) ? hB : hA);
    float* hout      = (i & 1) ? hA : hB;
    for (int idx = tid; idx < 8 * 768; idx += 512) {
      int bl = idx / 768, k = idx - bl * 768;
      sm[bl * 1284 + k] = xbuf[(b0d + bl) * 768 + k];
    }
    for (int idx = tid; idx < 8 * 512; idx += 512) {
      int bl = idx >> 9, k = idx & 511;
      sm[bl * 1284 + 768 + k] = hin[(b0d + bl) * 512 + k];
    }
    __syncthreads();
    {
      const int b_l = tid & 7, u_l = (tid >> 3) & 31, kp = tid >> 8;
      const int u = u0d + u_l;
      const float* xr = sm + b_l * 1284;
      float ar = 0, az = 0, ain = 0, ahn = 0;
      const float* wr = dWi + u * 768;
      const float* wz = dWi + (512 + u) * 768;
      const float* wn = dWi + (1024 + u) * 768;
      if (kp == 0) {
        for (int k = 0; k < 640; k += 4) {
          float4 xv = *(const float4*)(xr + k);
          float4 w;
          w = *(const float4*)(wr + k); ar  = D4(ar);
          w = *(const float4*)(wz + k); az  = D4(az);
          w = *(const float4*)(wn + k); ain = D4(ain);
        }
      } else {
        for (int k = 640; k < 768; k += 4) {
          float4 xv = *(const float4*)(xr + k);
          float4 w;
          w = *(const float4*)(wr + k); ar  = D4(ar);
          w = *(const float4*)(wz + k); az  = D4(az);
          w = *(const float4*)(wn + k); ain = D4(ain);
        }
        const float* hr = dWh + u * 512;
        const float* hz = dWh + (512 + u) * 512;
        const float* hn_ = dWh + (1024 + u) * 512;
        for (int k = 0; k < 512; k += 4) {
          float4 xv = *(const float4*)(xr + 768 + k);
          float4 w;
          w = *(const float4*)(hr + k);  ar  = D4(ar);
          w = *(const float4*)(hz + k);  az  = D4(az);
          w = *(const float4*)(hn_ + k); ahn = D4(ahn);
        }
      }
      float* pp = sm + 10272 + ((kp * 8 + b_l) * 32 + u_l) * 4;
      pp[0] = ar; pp[1] = az; pp[2] = ain; pp[3] = ahn;
    }
    __syncthreads();
    if (tid < 256) {
      const int b_l = tid & 7, u_l = tid >> 3;
      const float* p0 = sm + 10272 + ((b_l) * 32 + u_l) * 4;
      const float* p1 = sm + 10272 + ((8 + b_l) * 32 + u_l) * 4;
      float ar = p0[0] + p1[0], az = p0[1] + p1[1];
      float ain = p0[2] + p1[2], ahn = p0[3] + p1[3];
      const int u = u0d + u_l, b = b0d + b_l;
      float r = sigmoidf_(ar + dbi[u] + dbh[u]);
      float z = sigmoidf_(az + dbi[512 + u] + dbh[512 + u]);
      float n = fast_tanh(ain + dbi[1024 + u] + r * (ahn + dbh[1024 + u]));
      float hp = sm[b_l * 1284 + 768 + u];
      float hnv = (1.f - z) * n + z * hp;
      hout[b * 512 + u] = hnv;
      sm[12320 + b_l * 32 + u_l] = hnv;   // stash for epilogue
    }
    __syncthreads();
    for (int o = tid; o < 768; o += 512) {
      float acc[8];
#pragma unroll
      for (int b = 0; b < 8; ++b) acc[b] = 0.f;
      for (int k = 0; k < 32; ++k) {
        float w = WC[(u0d + k) * 768 + o];
#pragma unroll
        for (int b = 0; b < 8; ++b) acc[b] = fmaf(sm[12320 + b * 32 + k], w, acc[b]);
      }
#pragma unroll
      for (int b = 0; b < 8; ++b) qpart[(ut_d * 128 + b0d + b) * 768 + o] = acc[b];
    }
    gbar(slots, flg, ++ep);
  }
}

extern "C" void kernel_launch(void* const* d_in, const int* in_sizes, int n_in,
                              void* d_out, int out_size, void* d_ws, size_t ws_size,
                              hipStream_t stream) {
  (void)in_sizes; (void)n_in; (void)out_size; (void)ws_size;
  const float* inputs  = (const float*)d_in[0];
  const int*   lengths = (const int*)d_in[1];
  const int*   targets = (const int*)d_in[2];
  const float* W_in    = (const float*)d_in[3];
  const float* b_in    = (const float*)d_in[4];
  const float* enc_Wi  = (const float*)d_in[5];
  const float* enc_Wh  = (const float*)d_in[6];
  const float* enc_bi  = (const float*)d_in[7];
  const float* enc_bh  = (const float*)d_in[8];
  const float* dec_Wi  = (const float*)d_in[9];
  const float* dec_Wh  = (const float*)d_in[10];
  const float* dec_bi  = (const float*)d_in[11];
  const float* dec_bh  = (const float*)d_in[12];
  const float* s2s_Wq  = (const float*)d_in[13];
  const float* s2s_Wk  = (const float*)d_in[14];
  const float* s2s_v   = (const float*)d_in[15];
  const float* W_out   = (const float*)d_in[16];
  const float* b_out   = (const float*)d_in[17];
  const float* ptr_Wq  = (const float*)d_in[18];
  const float* ptr_Wk  = (const float*)d_in[19];
  const float* ptr_v   = (const float*)d_in[20];

  float* ws = (float*)d_ws;
  float* logits = (float*)d_out;
  float* preds  = (float*)d_out + 128 * 64 * 64;

  k_init2<<<256, 256, 0, stream>>>(ws + OFF_HA, (int*)(ws + OFF_SMASK),
                                   (unsigned*)(ws + OFF_SLOTS),
                                   (unsigned*)(ws + OFF_FLG));
  k_persist<<<256, 512, 0, stream>>>(inputs, lengths, targets, W_in, b_in,
                                     enc_Wi, enc_Wh, enc_bi, enc_bh,
                                     dec_Wi, dec_Wh, dec_bi, dec_bh,
                                     s2s_Wq, s2s_Wk, s2s_v, W_out, b_out,
                                     ptr_Wq, ptr_Wk, ptr_v,
                                     ws, logits, preds);
}

// Round 5
// 12081.265 us; speedup vs baseline: 2.1734x; 1.3758x over previous
//
#include <hip/hip_runtime.h>

#define NEGC (-1e9f)

// ws offsets (floats)
#define OFF_DENSE   0           //  2,097,152  [B*L*D]
#define OFF_ENCOUT  2097152     //  4,194,304  [B*L*H]
#define OFF_ENCKEYS 6291456     //  4,194,304  [B*L*512]
#define OFF_PTRKEYS 10485760    //  2,097,152  [B*L*256]
#define OFF_X       12582912    //     98,304  [B*768]  (ctx|dec_in)
#define OFF_HA      12681216    //     65,536
#define OFF_HB      12746752    //     65,536
#define OFF_H0      12812288    //     65,536
#define OFF_WC      12877824    //    393,216  [512 h][768 o] = [s2s_Wq | W_out^T@ptr_Wq]
#define OFF_BQ      13271040    //        256
#define OFF_QPART   13271296    //  1,572,864  [16 ut][128 b][768 o]
#define OFF_SMASK   14844160    //      8,192 ints
#define OFF_SLOTS   14852352    //      4,096 uints (256 slots, 64B stride)
#define OFF_FLG     14856448    //         16 uints
// total ~14,856,464 floats = 59.4 MB

__device__ __forceinline__ float fast_tanh(float x) {
  float e = __expf(2.0f * x);
  return 1.0f - 2.0f / (e + 1.0f);
}
__device__ __forceinline__ float sigmoidf_(float x) {
  return 1.0f / (1.0f + __expf(-x));
}
__device__ __forceinline__ float wsum(float v) {
#pragma unroll
  for (int o = 32; o > 0; o >>= 1) v += __shfl_xor(v, o);
  return v;
}
#define D4(acc) fmaf(xv.x, w.x, fmaf(xv.y, w.y, fmaf(xv.z, w.z, fmaf(xv.w, w.w, acc))))

// Coherent (L1/L2-bypassing, L3-coherence-point) accesses for cross-block data.
// Relaxed agent-scope atomics compile to sc0|sc1-flagged global ld/st — NO
// cache-wide buffer_inv / buffer_wbl2 (those only come from fences, which we
// never execute in steady state — that was R4's 9.9 GB refetch bug).
__device__ __forceinline__ float cohLd(const float* p) {
  return __hip_atomic_load((float*)p, __ATOMIC_RELAXED, __HIP_MEMORY_SCOPE_AGENT);
}
__device__ __forceinline__ void cohSt(float* p, float v) {
  __hip_atomic_store(p, v, __ATOMIC_RELAXED, __HIP_MEMORY_SCOPE_AGENT);
}

// ---- fence-free grid barrier: per-block slots + single aggregator ----
// Release slot-store orders prior coherent data stores (vmcnt drain); waiters
// poll relaxed. Plain-load buffers are write-once and first-read only after
// their producing barrier, so no acquire invalidate is needed.
__device__ __forceinline__ void gbar(unsigned* slots, unsigned* flg, unsigned e) {
  __syncthreads();
  const int tid = threadIdx.x;
  if (blockIdx.x == 0) {
    if (tid < 64) {
      if (tid == 0)
        __hip_atomic_store(slots, e, __ATOMIC_RELEASE, __HIP_MEMORY_SCOPE_AGENT);
      int done;
      do {
        done = 1;
#pragma unroll
        for (int j = 0; j < 4; ++j) {
          unsigned v = __hip_atomic_load(slots + ((tid * 4 + j) << 4),
                                         __ATOMIC_RELAXED, __HIP_MEMORY_SCOPE_AGENT);
          done &= (v >= e);
        }
      } while (!__all(done));
      if (tid == 0)
        __hip_atomic_store(flg, e, __ATOMIC_RELEASE, __HIP_MEMORY_SCOPE_AGENT);
    }
  } else {
    if (tid == 0) {
      __hip_atomic_store(slots + (blockIdx.x << 4), e, __ATOMIC_RELEASE,
                         __HIP_MEMORY_SCOPE_AGENT);
      while (__hip_atomic_load(flg, __ATOMIC_RELAXED, __HIP_MEMORY_SCOPE_AGENT) < e)
        __builtin_amdgcn_s_sleep(1);
    }
  }
  __syncthreads();
}

__global__ __launch_bounds__(256)
void k_init2(float* hA, int* smask, unsigned* slots, unsigned* flg) {
  int idx = blockIdx.x * 256 + threadIdx.x;   // grid 256*256 = 65536
  if (idx < 65536) hA[idx] = 0.f;
  if (idx < 8192) smask[idx] = 1;
  if (idx < 4096) slots[idx] = 0;
  if (idx < 16) flg[idx] = 0;
}

// ---------------- decoder phase 1 (attention + pointer output) ----------------
__device__ __forceinline__ void dec_p1(
    int i, float* sm, int tid, int bid,
    const float* qpart, const float* bq, const float* enc_keys,
    const float* ptr_keys, const float* enc_out, const float* dense,
    const float* sv_g, const float* pv_g, const int* lengths,
    const int* targets, int* smask, float* xbuf, float* logits, float* preds) {
  const int wv = tid >> 6, ln = tid & 63;
  if (bid < 128) {
    if (i < 64) {
      const int b = bid;
      const int lenb = lengths[b];
      {  // reduce q (o<512) over 16 u-tiles (qpart changes every step -> cohLd)
        float s = 0.f;
#pragma unroll
        for (int ut = 0; ut < 16; ++ut) s += cohLd(&qpart[(ut * 128 + b) * 768 + tid]);
        sm[tid] = s;            // sq
        sm[512 + tid] = sv_g[tid];  // sv
      }
      __syncthreads();
#pragma unroll
      for (int li = 0; li < 8; ++li) {
        int l = wv * 8 + li;
        float acc = 0.f;
#pragma unroll
        for (int c = 0; c < 8; ++c) {
          int a = c * 64 + ln;
          acc = fmaf(fast_tanh(sm[a] + enc_keys[(b * 64 + l) * 512 + a]), sm[512 + a], acc);
        }
        acc = wsum(acc);
        if (ln == 0) sm[1024 + l] = ((i < lenb) && (l < lenb)) ? acc : NEGC;
      }
      __syncthreads();
      if (tid < 64) {
        float v = sm[1024 + tid];
        float m = v;
#pragma unroll
        for (int off = 32; off > 0; off >>= 1) m = fmaxf(m, __shfl_xor(m, off));
        float e = __expf(v - m);
        float s = e;
#pragma unroll
        for (int off = 32; off > 0; off >>= 1) s += __shfl_xor(s, off);
        sm[1088 + tid] = e / s;
      }
      __syncthreads();
      {
        float c = 0.f;
#pragma unroll 8
        for (int l = 0; l < 64; ++l)
          c = fmaf(sm[1088 + l], enc_out[(b * 64 + l) * 512 + tid], c);
        cohSt(&xbuf[b * 768 + tid], c);
      }
      if (tid < 256) {
        int idx = (i == 0) ? 0 : targets[b * 64 + i - 1];
        cohSt(&xbuf[b * 768 + 512 + tid], dense[(b * 64 + idx) * 256 + tid]);
      }
    }
  } else {
    if (i >= 1) {
      const int b = bid - 128, j = i - 1;
      const int lenb = lengths[b];
      if (tid < 256) {
        float s = 0.f;
#pragma unroll
        for (int ut = 0; ut < 16; ++ut) s += cohLd(&qpart[(ut * 128 + b) * 768 + 512 + tid]);
        sm[tid] = s + bq[tid];      // spq
        sm[512 + tid] = pv_g[tid];  // pv
      }
      __syncthreads();
#pragma unroll
      for (int li = 0; li < 8; ++li) {
        int l = wv * 8 + li;
        float acc = 0.f;
#pragma unroll
        for (int c = 0; c < 4; ++c) {
          int a = c * 64 + ln;
          acc = fmaf(fast_tanh(sm[a] + ptr_keys[(b * 64 + l) * 256 + a]), sm[512 + a], acc);
        }
        acc = wsum(acc);
        if (ln == 0) sm[1024 + l] = acc;
      }
      __syncthreads();
      if (tid < 64) {
        int l = tid;
        bool pm = (j < lenb) && (l < lenb) && (smask[b * 64 + l] != 0);
        float v = pm ? sm[1024 + l] : NEGC;
        logits[(b * 64 + j) * 64 + l] = v;
        float bv = v; int bidx = l;
#pragma unroll
        for (int off = 32; off > 0; off >>= 1) {
          float ov = __shfl_xor(bv, off);
          int oi = __shfl_xor(bidx, off);
          if (ov > bv || (ov == bv && oi < bidx)) { bv = ov; bidx = oi; }
        }
        if (l == 0) preds[b * 64 + j] = (float)bidx;
        if (l == 0) smask[b * 64 + targets[b * 64 + j]] = 0;  // block-private
      }
    }
  }
}

// ---------------- the persistent kernel ----------------
__global__ __launch_bounds__(512, 2)
void k_persist(const float* __restrict__ inp, const int* __restrict__ lengths,
               const int* __restrict__ targets,
               const float* __restrict__ W_in, const float* __restrict__ b_in,
               const float* __restrict__ eWi, const float* __restrict__ eWh,
               const float* __restrict__ ebi, const float* __restrict__ ebh,
               const float* __restrict__ dWi, const float* __restrict__ dWh,
               const float* __restrict__ dbi, const float* __restrict__ dbh,
               const float* __restrict__ Wq, const float* __restrict__ Wk,
               const float* __restrict__ sv_g,
               const float* __restrict__ W_out, const float* __restrict__ b_out,
               const float* __restrict__ pWq, const float* __restrict__ pWk,
               const float* __restrict__ pv_g,
               float* __restrict__ ws, float* __restrict__ logits,
               float* __restrict__ preds) {
  __shared__ float sm[14400];   // 57.6 KB — sized by encoder phase (12352 xs + 2048 part)
  float* dense    = ws + OFF_DENSE;
  float* enc_out  = ws + OFF_ENCOUT;
  float* enc_keys = ws + OFF_ENCKEYS;
  float* ptr_keys = ws + OFF_PTRKEYS;
  float* xbuf     = ws + OFF_X;
  float* hA       = ws + OFF_HA;
  float* hB       = ws + OFF_HB;
  float* h0v      = ws + OFF_H0;
  float* WC       = ws + OFF_WC;
  float* bq       = ws + OFF_BQ;
  float* qpart    = ws + OFF_QPART;
  int*   smask    = (int*)(ws + OFF_SMASK);
  unsigned* slots = (unsigned*)(ws + OFF_SLOTS);
  unsigned* flg   = (unsigned*)(ws + OFF_FLG);

  const int tid = threadIdx.x, bid = blockIdx.x;
  unsigned ep = 0;

  // XCD-aware tile swizzle: all blocks on one XCD (bid&7) share u-tiles so the
  // per-XCD weight working set (~0.6-1.0 MB) stays L2-resident across steps.
  const int xcd = bid & 7, loc = bid >> 3;
  const int ut_e = (xcd << 2) | (loc & 3), bt_e = loc >> 2;   // enc: 32 ut x 8 bt
  const int ut_d = (xcd << 1) | (loc & 1), bt_d = loc >> 1;   // dec: 16 ut x 16 bt
  const int b0e = bt_e * 16, u0e = ut_e * 16;
  const int b0d = bt_d * 8,  u0d = ut_d * 32;

  // ================= P0a: dense_inputs =================
  for (int idx = bid * 8192 + tid; idx < (bid + 1) * 8192; idx += 512) {
    int bl = idx >> 8, d = idx & 255;
    cohSt(&dense[idx], fmaf(inp[bl * 2], W_in[d * 2],
                       fmaf(inp[bl * 2 + 1], W_in[d * 2 + 1], b_in[d])));
  }
  gbar(slots, flg, ++ep);

  // ================= P0b: WC, bq, ptr_keys =================
#pragma unroll
  for (int t2 = 0; t2 < 2; ++t2) {
    int idx = bid * 1024 + t2 * 512 + tid;
    int h = idx >> 9, a = idx & 511;
    cohSt(&WC[h * 768 + a], Wq[idx]);
  }
  {
    int j = bid * 512 + tid;
    int h = j >> 8, a = j & 255;
    float acc = 0.f;
    for (int d = 0; d < 256; ++d)
      acc = fmaf(W_out[d * 512 + h], pWq[d * 256 + a], acc);
    cohSt(&WC[h * 768 + 512 + a], acc);
  }
  if (bid == 0 && tid < 256) {
    float acc = 0.f;
    for (int d = 0; d < 256; ++d) acc = fmaf(b_out[d], pWq[d * 256 + tid], acc);
    cohSt(&bq[tid], acc);
  }
  {
    const int r0 = bid * 32;
    for (int idx = tid; idx < 32 * 256; idx += 512) {
      int r = idx >> 8, d = idx & 255;
      sm[r * 260 + d] = dense[(r0 + r) * 256 + d];   // plain: first read post-barrier
    }
    __syncthreads();
    const int o = tid & 255, rh = tid >> 8;
    float acc[16];
#pragma unroll
    for (int ri = 0; ri < 16; ++ri) acc[ri] = 0.f;
    for (int d = 0; d < 256; ++d) {
      float w = pWk[d * 256 + o];
#pragma unroll
      for (int ri = 0; ri < 16; ++ri)
        acc[ri] = fmaf(sm[(rh * 16 + ri) * 260 + d], w, acc[ri]);
    }
#pragma unroll
    for (int ri = 0; ri < 16; ++ri)
      cohSt(&ptr_keys[(r0 + rh * 16 + ri) * 256 + o], acc[ri]);
  }
  gbar(slots, flg, ++ep);

  // ================= Encoder: 64 GRU steps =================
  for (int t = 0; t < 64; ++t) {
    const float* hin = (t & 1) ? hB : hA;
    float* hout      = (t & 1) ? hA : hB;
    for (int idx = tid; idx < 16 * 512; idx += 512) {     // h part (mutable -> cohLd)
      int bl = idx >> 9, k = idx & 511;
      sm[bl * 772 + k] = cohLd(&hin[(b0e + bl) * 512 + k]);
    }
    for (int idx = tid; idx < 16 * 256; idx += 512) {     // dense part (const -> plain)
      int bl = idx >> 8, k = idx & 255;
      sm[bl * 772 + 512 + k] = dense[((b0e + bl) * 64 + t) * 256 + k];
    }
    __syncthreads();
    {
      const int b_l = tid & 15, u_l = (tid >> 4) & 15, kp = tid >> 8;
      const int u = u0e + u_l;
      const float* xr = sm + b_l * 772;
      float ar = 0, az = 0, ain = 0, ahn = 0;
      if (kp == 0) {
        const float* wr = eWh + u * 512;
        const float* wz = eWh + (512 + u) * 512;
        const float* wn = eWh + (1024 + u) * 512;
        for (int k = 0; k < 384; k += 4) {
          float4 xv = *(const float4*)(xr + k);
          float4 w;
          w = *(const float4*)(wr + k); ar  = D4(ar);
          w = *(const float4*)(wz + k); az  = D4(az);
          w = *(const float4*)(wn + k); ahn = D4(ahn);
        }
      } else {
        const float* wr = eWh + u * 512;
        const float* wz = eWh + (512 + u) * 512;
        const float* wn = eWh + (1024 + u) * 512;
        for (int k = 384; k < 512; k += 4) {
          float4 xv = *(const float4*)(xr + k);
          float4 w;
          w = *(const float4*)(wr + k); ar  = D4(ar);
          w = *(const float4*)(wz + k); az  = D4(az);
          w = *(const float4*)(wn + k); ahn = D4(ahn);
        }
        const float* vr = eWi + u * 256;
        const float* vz = eWi + (512 + u) * 256;
        const float* vn = eWi + (1024 + u) * 256;
        for (int k = 0; k < 256; k += 4) {
          float4 xv = *(const float4*)(xr + 512 + k);
          float4 w;
          w = *(const float4*)(vr + k); ar  = D4(ar);
          w = *(const float4*)(vz + k); az  = D4(az);
          w = *(const float4*)(vn + k); ain = D4(ain);
        }
      }
      float* pp = sm + 12352 + ((kp * 16 + b_l) * 16 + u_l) * 4;
      pp[0] = ar; pp[1] = az; pp[2] = ain; pp[3] = ahn;
    }
    __syncthreads();
    if (tid < 256) {
      const int b_l = tid & 15, u_l = tid >> 4;
      const float* p0 = sm + 12352 + ((b_l) * 16 + u_l) * 4;
      const float* p1 = sm + 12352 + ((16 + b_l) * 16 + u_l) * 4;
      float ar = p0[0] + p1[0], az = p0[1] + p1[1];
      float ain = p0[2] + p1[2], ahn = p0[3] + p1[3];
      const int u = u0e + u_l, b = b0e + b_l;
      float r = sigmoidf_(ar + ebi[u] + ebh[u]);
      float z = sigmoidf_(az + ebi[512 + u] + ebh[512 + u]);
      float n = fast_tanh(ain + ebi[1024 + u] + r * (ahn + ebh[1024 + u]));
      float hp = sm[b_l * 772 + u];
      float hn = (1.f - z) * n + z * hp;
      cohSt(&hout[b * 512 + u], hn);
      int lenb = lengths[b];
      cohSt(&enc_out[(b * 64 + t) * 512 + u], (t < lenb) ? hn : 0.f);
      if (t == lenb - 1) cohSt(&h0v[b * 512 + u], hn);
    }
    gbar(slots, flg, ++ep);
  }

  // ================= EK: enc_keys + qpart(h0) =================
#pragma unroll 1
  for (int pass = 0; pass < 2; ++pass) {
    const int r0 = bid * 32 + pass * 16;
    for (int idx = tid; idx < 16 * 512; idx += 512) {
      int r = idx >> 9, h = idx & 511;
      sm[r * 516 + h] = enc_out[(r0 + r) * 512 + h];   // plain: const post-encoder
    }
    __syncthreads();
    float acc[16];
#pragma unroll
    for (int ri = 0; ri < 16; ++ri) acc[ri] = 0.f;
    for (int h = 0; h < 512; ++h) {
      float w = Wk[h * 512 + tid];
#pragma unroll
      for (int ri = 0; ri < 16; ++ri) acc[ri] = fmaf(sm[ri * 516 + h], w, acc[ri]);
    }
#pragma unroll
    for (int ri = 0; ri < 16; ++ri) cohSt(&enc_keys[(r0 + ri) * 512 + tid], acc[ri]);
    __syncthreads();
  }
  {  // qpart from h0
    if (tid < 256) sm[tid] = h0v[(b0d + (tid >> 5)) * 512 + u0d + (tid & 31)];
    __syncthreads();
    for (int o = tid; o < 768; o += 512) {
      float acc[8];
#pragma unroll
      for (int b = 0; b < 8; ++b) acc[b] = 0.f;
      for (int k = 0; k < 32; ++k) {
        float w = WC[(u0d + k) * 768 + o];
#pragma unroll
        for (int b = 0; b < 8; ++b) acc[b] = fmaf(sm[b * 32 + k], w, acc[b]);
      }
#pragma unroll
      for (int b = 0; b < 8; ++b) cohSt(&qpart[(ut_d * 128 + b0d + b) * 768 + o], acc[b]);
    }
  }
  gbar(slots, flg, ++ep);

  // ================= Decoder: 64 steps, 2 barriers each =================
  for (int i = 0; i <= 64; ++i) {
    dec_p1(i, sm, tid, bid, qpart, bq, enc_keys, ptr_keys, enc_out, dense,
           sv_g, pv_g, lengths, targets, smask, xbuf, logits, preds);
    if (i == 64) break;
    gbar(slots, flg, ++ep);

    // ---- D2: GRU gates GEMM + pointwise + split-K q/pq epilogue ----
    const float* hin = (i == 0) ? h0v : ((i & 1) ? hB : hA);
    float* hout      = (i & 1) ? hA : hB;
    for (int idx = tid; idx < 8 * 768; idx += 512) {     // xbuf mutable -> cohLd
      int bl = idx / 768, k = idx - bl * 768;
      sm[bl * 1284 + k] = cohLd(&xbuf[(b0d + bl) * 768 + k]);
    }
    for (int idx = tid; idx < 8 * 512; idx += 512) {     // h mutable -> cohLd
      int bl = idx >> 9, k = idx & 511;
      sm[bl * 1284 + 768 + k] = cohLd(&hin[(b0d + bl) * 512 + k]);
    }
    __syncthreads();
    {
      const int b_l = tid & 7, u_l = (tid >> 3) & 31, kp = tid >> 8;
      const int u = u0d + u_l;
      const float* xr = sm + b_l * 1284;
      float ar = 0, az = 0, ain = 0, ahn = 0;
      const float* wr = dWi + u * 768;
      const float* wz = dWi + (512 + u) * 768;
      const float* wn = dWi + (1024 + u) * 768;
      if (kp == 0) {
        for (int k = 0; k < 640; k += 4) {
          float4 xv = *(const float4*)(xr + k);
          float4 w;
          w = *(const float4*)(wr + k); ar  = D4(ar);
          w = *(const float4*)(wz + k); az  = D4(az);
          w = *(const float4*)(wn + k); ain = D4(ain);
        }
      } else {
        for (int k = 640; k < 768; k += 4) {
          float4 xv = *(const float4*)(xr + k);
          float4 w;
          w = *(const float4*)(wr + k); ar  = D4(ar);
          w = *(const float4*)(wz + k); az  = D4(az);
          w = *(const float4*)(wn + k); ain = D4(ain);
        }
        const float* hr = dWh + u * 512;
        const float* hz = dWh + (512 + u) * 512;
        const float* hn_ = dWh + (1024 + u) * 512;
        for (int k = 0; k < 512; k += 4) {
          float4 xv = *(const float4*)(xr + 768 + k);
          float4 w;
          w = *(const float4*)(hr + k);  ar  = D4(ar);
          w = *(const float4*)(hz + k);  az  = D4(az);
          w = *(const float4*)(hn_ + k); ahn = D4(ahn);
        }
      }
      float* pp = sm + 10272 + ((kp * 8 + b_l) * 32 + u_l) * 4;
      pp[0] = ar; pp[1] = az; pp[2] = ain; pp[3] = ahn;
    }
    __syncthreads();
    if (tid < 256) {
      const int b_l = tid & 7, u_l = tid >> 3;
      const float* p0 = sm + 10272 + ((b_l) * 32 + u_l) * 4;
      const float* p1 = sm + 10272 + ((8 + b_l) * 32 + u_l) * 4;
      float ar = p0[0] + p1[0], az = p0[1] + p1[1];
      float ain = p0[2] + p1[2], ahn = p0[3] + p1[3];
      const int u = u0d + u_l, b = b0d + b_l;
      float r = sigmoidf_(ar + dbi[u] + dbh[u]);
      float z = sigmoidf_(az + dbi[512 + u] + dbh[512 + u]);
      float n = fast_tanh(ain + dbi[1024 + u] + r * (ahn + dbh[1024 + u]));
      float hp = sm[b_l * 1284 + 768 + u];
      float hnv = (1.f - z) * n + z * hp;
      cohSt(&hout[b * 512 + u], hnv);
      sm[12320 + b_l * 32 + u_l] = hnv;   // stash for epilogue
    }
    __syncthreads();
    for (int o = tid; o < 768; o += 512) {
      float acc[8];
#pragma unroll
      for (int b = 0; b < 8; ++b) acc[b] = 0.f;
      for (int k = 0; k < 32; ++k) {
        float w = WC[(u0d + k) * 768 + o];
#pragma unroll
        for (int b = 0; b < 8; ++b) acc[b] = fmaf(sm[12320 + b * 32 + k], w, acc[b]);
      }
#pragma unroll
      for (int b = 0; b < 8; ++b) cohSt(&qpart[(ut_d * 128 + b0d + b) * 768 + o], acc[b]);
    }
    gbar(slots, flg, ++ep);
  }
}

extern "C" void kernel_launch(void* const* d_in, const int* in_sizes, int n_in,
                              void* d_out, int out_size, void* d_ws, size_t ws_size,
                              hipStream_t stream) {
  (void)in_sizes; (void)n_in; (void)out_size; (void)ws_size;
  const float* inputs  = (const float*)d_in[0];
  const int*   lengths = (const int*)d_in[1];
  const int*   targets = (const int*)d_in[2];
  const float* W_in    = (const float*)d_in[3];
  const float* b_in    = (const float*)d_in[4];
  const float* enc_Wi  = (const float*)d_in[5];
  const float* enc_Wh  = (const float*)d_in[6];
  const float* enc_bi  = (const float*)d_in[7];
  const float* enc_bh  = (const float*)d_in[8];
  const float* dec_Wi  = (const float*)d_in[9];
  const float* dec_Wh  = (const float*)d_in[10];
  const float* dec_bi  = (const float*)d_in[11];
  const float* dec_bh  = (const float*)d_in[12];
  const float* s2s_Wq  = (const float*)d_in[13];
  const float* s2s_Wk  = (const float*)d_in[14];
  const float* s2s_v   = (const float*)d_in[15];
  const float* W_out   = (const float*)d_in[16];
  const float* b_out   = (const float*)d_in[17];
  const float* ptr_Wq  = (const float*)d_in[18];
  const float* ptr_Wk  = (const float*)d_in[19];
  const float* ptr_v   = (const float*)d_in[20];

  float* ws = (float*)d_ws;
  float* logits = (float*)d_out;
  float* preds  = (float*)d_out + 128 * 64 * 64;

  k_init2<<<256, 256, 0, stream>>>(ws + OFF_HA, (int*)(ws + OFF_SMASK),
                                   (unsigned*)(ws + OFF_SLOTS),
                                   (unsigned*)(ws + OFF_FLG));
  k_persist<<<256, 512, 0, stream>>>(inputs, lengths, targets, W_in, b_in,
                                     enc_Wi, enc_Wh, enc_bi, enc_bh,
                                     dec_Wi, dec_Wh, dec_bi, dec_bh,
                                     s2s_Wq, s2s_Wk, s2s_v, W_out, b_out,
                                     ptr_Wq, ptr_Wk, ptr_v,
                                     ws, logits, preds);
}

// Round 6
// 9681.786 us; speedup vs baseline: 2.7120x; 1.2478x over previous
//
#include <hip/hip_runtime.h>

#define NEGC (-1e9f)

// ws offsets (floats)
#define OFF_DENSE   0           //  2,097,152  [B*L*D]
#define OFF_ENCOUT  2097152     //  4,194,304  [B*L*H]
#define OFF_ENCKEYS 6291456     //  4,194,304  [B*L*512]
#define OFF_PTRKEYS 10485760    //  2,097,152  [B*L*256]
#define OFF_X       12582912    //     98,304  [B*768]  (ctx|dec_in)
#define OFF_HA      12681216    //     65,536
#define OFF_HB      12746752    //     65,536
#define OFF_H0      12812288    //     65,536
#define OFF_WC      12877824    //    393,216  [512 h][768 o] = [s2s_Wq | W_out^T@ptr_Wq]
#define OFF_BQ      13271040    //        256
#define OFF_QPART   13271296    //  1,572,864  [16 ut][128 b][768 o]
#define OFF_SMASK   14844160    //      8,192 ints
#define OFF_SLOTS   14852352    //      4,096 uints (256 slots, 64B stride)
#define OFF_FLG     14856448    //         16 uints
// total ~14,856,464 floats = 59.4 MB

typedef float f4v __attribute__((ext_vector_type(4)));

__device__ __forceinline__ f4v nt4(const float* p) {
  return __builtin_nontemporal_load((const f4v*)p);
}

__device__ __forceinline__ float fast_tanh(float x) {
  float e = __expf(2.0f * x);
  return 1.0f - 2.0f / (e + 1.0f);
}
__device__ __forceinline__ float sigmoidf_(float x) {
  return 1.0f / (1.0f + __expf(-x));
}
__device__ __forceinline__ float wsum(float v) {
#pragma unroll
  for (int o = 32; o > 0; o >>= 1) v += __shfl_xor(v, o);
  return v;
}
#define D4(acc) fmaf(xv.x, w.x, fmaf(xv.y, w.y, fmaf(xv.z, w.z, fmaf(xv.w, w.w, acc))))

// Coherent (cache-bypassing toward the L3 coherence point) accesses for
// cross-block mutable data. Relaxed agent-scope — no fences, no buffer_inv.
__device__ __forceinline__ float cohLd(const float* p) {
  return __hip_atomic_load((float*)p, __ATOMIC_RELAXED, __HIP_MEMORY_SCOPE_AGENT);
}
__device__ __forceinline__ void cohSt(float* p, float v) {
  __hip_atomic_store(p, v, __ATOMIC_RELAXED, __HIP_MEMORY_SCOPE_AGENT);
}

// ---- fence-free grid barrier: per-block slots + single aggregator ----
__device__ __forceinline__ void gbar(unsigned* slots, unsigned* flg, unsigned e) {
  __syncthreads();
  const int tid = threadIdx.x;
  if (blockIdx.x == 0) {
    if (tid < 64) {
      if (tid == 0)
        __hip_atomic_store(slots, e, __ATOMIC_RELEASE, __HIP_MEMORY_SCOPE_AGENT);
      int done;
      do {
        done = 1;
#pragma unroll
        for (int j = 0; j < 4; ++j) {
          unsigned v = __hip_atomic_load(slots + ((tid * 4 + j) << 4),
                                         __ATOMIC_RELAXED, __HIP_MEMORY_SCOPE_AGENT);
          done &= (v >= e);
        }
      } while (!__all(done));
      if (tid == 0)
        __hip_atomic_store(flg, e, __ATOMIC_RELEASE, __HIP_MEMORY_SCOPE_AGENT);
    }
  } else {
    if (tid == 0) {
      __hip_atomic_store(slots + (blockIdx.x << 4), e, __ATOMIC_RELEASE,
                         __HIP_MEMORY_SCOPE_AGENT);
      while (__hip_atomic_load(flg, __ATOMIC_RELAXED, __HIP_MEMORY_SCOPE_AGENT) < e)
        __builtin_amdgcn_s_sleep(1);
    }
  }
  __syncthreads();
}

__global__ __launch_bounds__(256)
void k_init2(float* hA, int* smask, unsigned* slots, unsigned* flg) {
  int idx = blockIdx.x * 256 + threadIdx.x;   // grid 256*256 = 65536
  if (idx < 65536) hA[idx] = 0.f;
  if (idx < 8192) smask[idx] = 1;
  if (idx < 4096) slots[idx] = 0;
  if (idx < 16) flg[idx] = 0;
}

// ---------------- decoder phase 1 (attention + pointer output) ----------------
__device__ __forceinline__ void dec_p1(
    int i, float* sm, int tid, int bid,
    const float* qpart, const float* bq, const float* enc_keys,
    const float* ptr_keys, const float* enc_out, const float* dense,
    const float* sv_g, const float* pv_g, const int* lengths,
    const int* targets, int* smask, float* xbuf, float* logits, float* preds) {
  const int wv = tid >> 6, ln = tid & 63;
  if (bid < 128) {
    if (i < 64) {
      const int b = bid;
      const int lenb = lengths[b];
      {  // reduce q (o<512) over 16 u-tiles
        float s = 0.f;
#pragma unroll
        for (int ut = 0; ut < 16; ++ut) s += cohLd(&qpart[(ut * 128 + b) * 768 + tid]);
        sm[tid] = s;            // sq
        sm[512 + tid] = sv_g[tid];  // sv
      }
      __syncthreads();
      {  // scores: lane ln owns a = ln*8..ln*8+7; enc_keys L2-RESIDENT (plain f4)
        const f4v q0 = *(const f4v*)(sm + ln * 8);
        const f4v q1 = *(const f4v*)(sm + ln * 8 + 4);
        const f4v v0 = *(const f4v*)(sm + 512 + ln * 8);
        const f4v v1 = *(const f4v*)(sm + 512 + ln * 8 + 4);
#pragma unroll
        for (int li = 0; li < 8; ++li) {
          int l = wv * 8 + li;
          const float* kp = enc_keys + (b * 64 + l) * 512 + ln * 8;
          f4v k0 = *(const f4v*)kp;
          f4v k1 = *(const f4v*)(kp + 4);
          float acc =
              fast_tanh(q0.x + k0.x) * v0.x + fast_tanh(q0.y + k0.y) * v0.y +
              fast_tanh(q0.z + k0.z) * v0.z + fast_tanh(q0.w + k0.w) * v0.w +
              fast_tanh(q1.x + k1.x) * v1.x + fast_tanh(q1.y + k1.y) * v1.y +
              fast_tanh(q1.z + k1.z) * v1.z + fast_tanh(q1.w + k1.w) * v1.w;
          acc = wsum(acc);
          if (ln == 0) sm[1024 + l] = ((i < lenb) && (l < lenb)) ? acc : NEGC;
        }
      }
      __syncthreads();
      if (tid < 64) {
        float v = sm[1024 + tid];
        float m = v;
#pragma unroll
        for (int off = 32; off > 0; off >>= 1) m = fmaxf(m, __shfl_xor(m, off));
        float e = __expf(v - m);
        float s = e;
#pragma unroll
        for (int off = 32; off > 0; off >>= 1) s += __shfl_xor(s, off);
        sm[1088 + tid] = e / s;
      }
      __syncthreads();
      {  // context: 4 groups x 128 lanes x f4; enc_out STREAMED (nt, no L2 alloc)
        const int g = tid >> 7, h4 = (tid & 127) * 4;
        f4v c = {0.f, 0.f, 0.f, 0.f};
#pragma unroll
        for (int lo = 0; lo < 16; ++lo) {
          int l = g * 16 + lo;
          float w = sm[1088 + l];
          f4v e = nt4(enc_out + (b * 64 + l) * 512 + h4);
          c += e * w;
        }
        *(f4v*)(sm + 1152 + (g * 128 + (tid & 127)) * 4) = c;
      }
      __syncthreads();
      if (tid < 128) {
        f4v r = *(const f4v*)(sm + 1152 + (0 * 128 + tid) * 4) +
                *(const f4v*)(sm + 1152 + (1 * 128 + tid) * 4) +
                *(const f4v*)(sm + 1152 + (2 * 128 + tid) * 4) +
                *(const f4v*)(sm + 1152 + (3 * 128 + tid) * 4);
        const int o = tid * 4;
        cohSt(&xbuf[b * 768 + o + 0], r.x);
        cohSt(&xbuf[b * 768 + o + 1], r.y);
        cohSt(&xbuf[b * 768 + o + 2], r.z);
        cohSt(&xbuf[b * 768 + o + 3], r.w);
      }
      if (tid < 256) {
        int idx = (i == 0) ? 0 : targets[b * 64 + i - 1];
        cohSt(&xbuf[b * 768 + 512 + tid],
              __builtin_nontemporal_load(dense + (b * 64 + idx) * 256 + tid));
      }
    }
  } else {
    if (i >= 1) {
      const int b = bid - 128, j = i - 1;
      const int lenb = lengths[b];
      if (tid < 256) {
        float s = 0.f;
#pragma unroll
        for (int ut = 0; ut < 16; ++ut) s += cohLd(&qpart[(ut * 128 + b) * 768 + 512 + tid]);
        sm[tid] = s + bq[tid];      // spq
        sm[512 + tid] = pv_g[tid];  // pv
      }
      __syncthreads();
      {  // ptr scores: lane ln owns a = ln*4..; ptr_keys STREAMED (nt)
        const f4v q = *(const f4v*)(sm + ln * 4);
        const f4v v = *(const f4v*)(sm + 512 + ln * 4);
#pragma unroll
        for (int li = 0; li < 8; ++li) {
          int l = wv * 8 + li;
          f4v k = nt4(ptr_keys + (b * 64 + l) * 256 + ln * 4);
          float acc = fast_tanh(q.x + k.x) * v.x + fast_tanh(q.y + k.y) * v.y +
                      fast_tanh(q.z + k.z) * v.z + fast_tanh(q.w + k.w) * v.w;
          acc = wsum(acc);
          if (ln == 0) sm[1024 + l] = acc;
        }
      }
      __syncthreads();
      if (tid < 64) {
        int l = tid;
        bool pm = (j < lenb) && (l < lenb) && (smask[b * 64 + l] != 0);
        float v = pm ? sm[1024 + l] : NEGC;
        logits[(b * 64 + j) * 64 + l] = v;
        float bv = v; int bidx = l;
#pragma unroll
        for (int off = 32; off > 0; off >>= 1) {
          float ov = __shfl_xor(bv, off);
          int oi = __shfl_xor(bidx, off);
          if (ov > bv || (ov == bv && oi < bidx)) { bv = ov; bidx = oi; }
        }
        if (l == 0) preds[b * 64 + j] = (float)bidx;
        if (l == 0) smask[b * 64 + targets[b * 64 + j]] = 0;  // block-private
      }
    }
  }
}

// ---------------- the persistent kernel ----------------
__global__ __launch_bounds__(512, 2)
void k_persist(const float* __restrict__ inp, const int* __restrict__ lengths,
               const int* __restrict__ targets,
               const float* __restrict__ W_in, const float* __restrict__ b_in,
               const float* __restrict__ eWi, const float* __restrict__ eWh,
               const float* __restrict__ ebi, const float* __restrict__ ebh,
               const float* __restrict__ dWi, const float* __restrict__ dWh,
               const float* __restrict__ dbi, const float* __restrict__ dbh,
               const float* __restrict__ Wq, const float* __restrict__ Wk,
               const float* __restrict__ sv_g,
               const float* __restrict__ W_out, const float* __restrict__ b_out,
               const float* __restrict__ pWq, const float* __restrict__ pWk,
               const float* __restrict__ pv_g,
               float* __restrict__ ws, float* __restrict__ logits,
               float* __restrict__ preds) {
  __shared__ float sm[14400];   // 57.6 KB — sized by encoder phase (12352 xs + 2048 part)
  float* dense    = ws + OFF_DENSE;
  float* enc_out  = ws + OFF_ENCOUT;
  float* enc_keys = ws + OFF_ENCKEYS;
  float* ptr_keys = ws + OFF_PTRKEYS;
  float* xbuf     = ws + OFF_X;
  float* hA       = ws + OFF_HA;
  float* hB       = ws + OFF_HB;
  float* h0v      = ws + OFF_H0;
  float* WC       = ws + OFF_WC;
  float* bq       = ws + OFF_BQ;
  float* qpart    = ws + OFF_QPART;
  int*   smask    = (int*)(ws + OFF_SMASK);
  unsigned* slots = (unsigned*)(ws + OFF_SLOTS);
  unsigned* flg   = (unsigned*)(ws + OFF_FLG);

  const int tid = threadIdx.x, bid = blockIdx.x;
  unsigned ep = 0;

  // XCD-aware tile swizzle: all blocks on one XCD (bid&7) share u-tiles so the
  // per-XCD resident set (enc_keys 2MB + dec weights 1.2MB + WC 0.2MB) < 4MB L2.
  const int xcd = bid & 7, loc = bid >> 3;
  const int ut_e = (xcd << 2) | (loc & 3), bt_e = loc >> 2;   // enc: 32 ut x 8 bt
  const int ut_d = (xcd << 1) | (loc & 1), bt_d = loc >> 1;   // dec: 16 ut x 16 bt
  const int b0e = bt_e * 16, u0e = ut_e * 16;
  const int b0d = bt_d * 8,  u0d = ut_d * 32;

  // ================= P0a: dense_inputs =================
  for (int idx = bid * 8192 + tid; idx < (bid + 1) * 8192; idx += 512) {
    int bl = idx >> 8, d = idx & 255;
    cohSt(&dense[idx], fmaf(inp[bl * 2], W_in[d * 2],
                       fmaf(inp[bl * 2 + 1], W_in[d * 2 + 1], b_in[d])));
  }
  gbar(slots, flg, ++ep);

  // ================= P0b: WC, bq, ptr_keys =================
#pragma unroll
  for (int t2 = 0; t2 < 2; ++t2) {
    int idx = bid * 1024 + t2 * 512 + tid;
    int h = idx >> 9, a = idx & 511;
    cohSt(&WC[h * 768 + a], Wq[idx]);
  }
  {
    int j = bid * 512 + tid;
    int h = j >> 8, a = j & 255;
    float acc = 0.f;
    for (int d = 0; d < 256; ++d)
      acc = fmaf(W_out[d * 512 + h], pWq[d * 256 + a], acc);
    cohSt(&WC[h * 768 + 512 + a], acc);
  }
  if (bid == 0 && tid < 256) {
    float acc = 0.f;
    for (int d = 0; d < 256; ++d) acc = fmaf(b_out[d], pWq[d * 256 + tid], acc);
    cohSt(&bq[tid], acc);
  }
  {
    const int r0 = bid * 32;
    for (int idx = tid; idx < 32 * 256; idx += 512) {
      int r = idx >> 8, d = idx & 255;
      sm[r * 260 + d] = dense[(r0 + r) * 256 + d];   // plain: first read post-barrier
    }
    __syncthreads();
    const int o = tid & 255, rh = tid >> 8;
    float acc[16];
#pragma unroll
    for (int ri = 0; ri < 16; ++ri) acc[ri] = 0.f;
    for (int d = 0; d < 256; ++d) {
      float w = pWk[d * 256 + o];
#pragma unroll
      for (int ri = 0; ri < 16; ++ri)
        acc[ri] = fmaf(sm[(rh * 16 + ri) * 260 + d], w, acc[ri]);
    }
#pragma unroll
    for (int ri = 0; ri < 16; ++ri)
      cohSt(&ptr_keys[(r0 + rh * 16 + ri) * 256 + o], acc[ri]);
  }
  gbar(slots, flg, ++ep);

  // ================= Encoder: 64 GRU steps =================
  for (int t = 0; t < 64; ++t) {
    const float* hin = (t & 1) ? hB : hA;
    float* hout      = (t & 1) ? hA : hB;
    for (int idx = tid; idx < 16 * 512; idx += 512) {     // h part (mutable -> cohLd)
      int bl = idx >> 9, k = idx & 511;
      sm[bl * 772 + k] = cohLd(&hin[(b0e + bl) * 512 + k]);
    }
    for (int v = tid; v < 16 * 64; v += 512) {            // dense slice: nt f4 stream
      int bl = v >> 6, k4 = (v & 63) * 4;
      *(f4v*)(sm + bl * 772 + 512 + k4) =
          nt4(dense + ((b0e + bl) * 64 + t) * 256 + k4);
    }
    __syncthreads();
    {
      const int b_l = tid & 15, u_l = (tid >> 4) & 15, kp = tid >> 8;
      const int u = u0e + u_l;
      const float* xr = sm + b_l * 772;
      float ar = 0, az = 0, ain = 0, ahn = 0;
      if (kp == 0) {
        const float* wr = eWh + u * 512;
        const float* wz = eWh + (512 + u) * 512;
        const float* wn = eWh + (1024 + u) * 512;
        for (int k = 0; k < 384; k += 4) {
          float4 xv = *(const float4*)(xr + k);
          float4 w;
          w = *(const float4*)(wr + k); ar  = D4(ar);
          w = *(const float4*)(wz + k); az  = D4(az);
          w = *(const float4*)(wn + k); ahn = D4(ahn);
        }
      } else {
        const float* wr = eWh + u * 512;
        const float* wz = eWh + (512 + u) * 512;
        const float* wn = eWh + (1024 + u) * 512;
        for (int k = 384; k < 512; k += 4) {
          float4 xv = *(const float4*)(xr + k);
          float4 w;
          w = *(const float4*)(wr + k); ar  = D4(ar);
          w = *(const float4*)(wz + k); az  = D4(az);
          w = *(const float4*)(wn + k); ahn = D4(ahn);
        }
        const float* vr = eWi + u * 256;
        const float* vz = eWi + (512 + u) * 256;
        const float* vn = eWi + (1024 + u) * 256;
        for (int k = 0; k < 256; k += 4) {
          float4 xv = *(const float4*)(xr + 512 + k);
          float4 w;
          w = *(const float4*)(vr + k); ar  = D4(ar);
          w = *(const float4*)(vz + k); az  = D4(az);
          w = *(const float4*)(vn + k); ain = D4(ain);
        }
      }
      float* pp = sm + 12352 + ((kp * 16 + b_l) * 16 + u_l) * 4;
      pp[0] = ar; pp[1] = az; pp[2] = ain; pp[3] = ahn;
    }
    __syncthreads();
    if (tid < 256) {
      const int b_l = tid & 15, u_l = tid >> 4;
      const float* p0 = sm + 12352 + ((b_l) * 16 + u_l) * 4;
      const float* p1 = sm + 12352 + ((16 + b_l) * 16 + u_l) * 4;
      float ar = p0[0] + p1[0], az = p0[1] + p1[1];
      float ain = p0[2] + p1[2], ahn = p0[3] + p1[3];
      const int u = u0e + u_l, b = b0e + b_l;
      float r = sigmoidf_(ar + ebi[u] + ebh[u]);
      float z = sigmoidf_(az + ebi[512 + u] + ebh[512 + u]);
      float n = fast_tanh(ain + ebi[1024 + u] + r * (ahn + ebh[1024 + u]));
      float hp = sm[b_l * 772 + u];
      float hn = (1.f - z) * n + z * hp;
      cohSt(&hout[b * 512 + u], hn);
      cohSt(&enc_out[(b * 64 + t) * 512 + u], (t < lengths[b]) ? hn : 0.f);
      if (t == lengths[b] - 1) cohSt(&h0v[b * 512 + u], hn);
    }
    gbar(slots, flg, ++ep);
  }

  // ================= EK: enc_keys + qpart(h0) =================
#pragma unroll 1
  for (int pass = 0; pass < 2; ++pass) {
    const int r0 = bid * 32 + pass * 16;
    for (int v = tid; v < 16 * 128; v += 512) {   // nt f4: don't pollute L2
      int r = v >> 7, h4 = (v & 127) * 4;
      *(f4v*)(sm + r * 516 + h4) = nt4(enc_out + (r0 + r) * 512 + h4);
    }
    __syncthreads();
    float acc[16];
#pragma unroll
    for (int ri = 0; ri < 16; ++ri) acc[ri] = 0.f;
    for (int h = 0; h < 512; ++h) {
      float w = Wk[h * 512 + tid];
#pragma unroll
      for (int ri = 0; ri < 16; ++ri) acc[ri] = fmaf(sm[ri * 516 + h], w, acc[ri]);
    }
#pragma unroll
    for (int ri = 0; ri < 16; ++ri) cohSt(&enc_keys[(r0 + ri) * 512 + tid], acc[ri]);
    __syncthreads();
  }
  {  // qpart from h0
    if (tid < 256) sm[tid] = h0v[(b0d + (tid >> 5)) * 512 + u0d + (tid & 31)];
    __syncthreads();
    for (int o = tid; o < 768; o += 512) {
      float acc[8];
#pragma unroll
      for (int b = 0; b < 8; ++b) acc[b] = 0.f;
      for (int k = 0; k < 32; ++k) {
        float w = WC[(u0d + k) * 768 + o];
#pragma unroll
        for (int b = 0; b < 8; ++b) acc[b] = fmaf(sm[b * 32 + k], w, acc[b]);
      }
#pragma unroll
      for (int b = 0; b < 8; ++b) cohSt(&qpart[(ut_d * 128 + b0d + b) * 768 + o], acc[b]);
    }
  }
  gbar(slots, flg, ++ep);

  // ================= Decoder: 64 steps, 2 barriers each =================
  for (int i = 0; i <= 64; ++i) {
    dec_p1(i, sm, tid, bid, qpart, bq, enc_keys, ptr_keys, enc_out, dense,
           sv_g, pv_g, lengths, targets, smask, xbuf, logits, preds);
    if (i == 64) break;
    gbar(slots, flg, ++ep);

    // ---- D2: GRU gates GEMM + pointwise + split-K q/pq epilogue ----
    const float* hin = (i == 0) ? h0v : ((i & 1) ? hB : hA);
    float* hout      = (i & 1) ? hA : hB;
    for (int idx = tid; idx < 8 * 768; idx += 512) {     // xbuf mutable -> cohLd
      int bl = idx / 768, k = idx - bl * 768;
      sm[bl * 1284 + k] = cohLd(&xbuf[(b0d + bl) * 768 + k]);
    }
    for (int idx = tid; idx < 8 * 512; idx += 512) {     // h mutable -> cohLd
      int bl = idx >> 9, k = idx & 511;
      sm[bl * 1284 + 768 + k] = cohLd(&hin[(b0d + bl) * 512 + k]);
    }
    __syncthreads();
    {
      const int b_l = tid & 7, u_l = (tid >> 3) & 31, kp = tid >> 8;
      const int u = u0d + u_l;
      const float* xr = sm + b_l * 1284;
      float ar = 0, az = 0, ain = 0, ahn = 0;
      const float* wr = dWi + u * 768;
      const float* wz = dWi + (512 + u) * 768;
      const float* wn = dWi + (1024 + u) * 768;
      if (kp == 0) {
        for (int k = 0; k < 640; k += 4) {
          float4 xv = *(const float4*)(xr + k);
          float4 w;
          w = *(const float4*)(wr + k); ar  = D4(ar);
          w = *(const float4*)(wz + k); az  = D4(az);
          w = *(const float4*)(wn + k); ain = D4(ain);
        }
      } else {
        for (int k = 640; k < 768; k += 4) {
          float4 xv = *(const float4*)(xr + k);
          float4 w;
          w = *(const float4*)(wr + k); ar  = D4(ar);
          w = *(const float4*)(wz + k); az  = D4(az);
          w = *(const float4*)(wn + k); ain = D4(ain);
        }
        const float* hr = dWh + u * 512;
        const float* hz = dWh + (512 + u) * 512;
        const float* hn_ = dWh + (1024 + u) * 512;
        for (int k = 0; k < 512; k += 4) {
          float4 xv = *(const float4*)(xr + 768 + k);
          float4 w;
          w = *(const float4*)(hr + k);  ar  = D4(ar);
          w = *(const float4*)(hz + k);  az  = D4(az);
          w = *(const float4*)(hn_ + k); ahn = D4(ahn);
        }
      }
      float* pp = sm + 10272 + ((kp * 8 + b_l) * 32 + u_l) * 4;
      pp[0] = ar; pp[1] = az; pp[2] = ain; pp[3] = ahn;
    }
    __syncthreads();
    if (tid < 256) {
      const int b_l = tid & 7, u_l = tid >> 3;
      const float* p0 = sm + 10272 + ((b_l) * 32 + u_l) * 4;
      const float* p1 = sm + 10272 + ((8 + b_l) * 32 + u_l) * 4;
      float ar = p0[0] + p1[0], az = p0[1] + p1[1];
      float ain = p0[2] + p1[2], ahn = p0[3] + p1[3];
      const int u = u0d + u_l, b = b0d + b_l;
      float r = sigmoidf_(ar + dbi[u] + dbh[u]);
      float z = sigmoidf_(az + dbi[512 + u] + dbh[512 + u]);
      float n = fast_tanh(ain + dbi[1024 + u] + r * (ahn + dbh[1024 + u]));
      float hp = sm[b_l * 1284 + 768 + u];
      float hnv = (1.f - z) * n + z * hp;
      cohSt(&hout[b * 512 + u], hnv);
      sm[12320 + b_l * 32 + u_l] = hnv;   // stash for epilogue
    }
    __syncthreads();
    for (int o = tid; o < 768; o += 512) {
      float acc[8];
#pragma unroll
      for (int b = 0; b < 8; ++b) acc[b] = 0.f;
      for (int k = 0; k < 32; ++k) {
        float w = WC[(u0d + k) * 768 + o];
#pragma unroll
        for (int b = 0; b < 8; ++b) acc[b] = fmaf(sm[12320 + b * 32 + k], w, acc[b]);
      }
#pragma unroll
      for (int b = 0; b < 8; ++b) cohSt(&qpart[(ut_d * 128 + b0d + b) * 768 + o], acc[b]);
    }
    gbar(slots, flg, ++ep);
  }
}

extern "C" void kernel_launch(void* const* d_in, const int* in_sizes, int n_in,
                              void* d_out, int out_size, void* d_ws, size_t ws_size,
                              hipStream_t stream) {
  (void)in_sizes; (void)n_in; (void)out_size; (void)ws_size;
  const float* inputs  = (const float*)d_in[0];
  const int*   lengths = (const int*)d_in[1];
  const int*   targets = (const int*)d_in[2];
  const float* W_in    = (const float*)d_in[3];
  const float* b_in    = (const float*)d_in[4];
  const float* enc_Wi  = (const float*)d_in[5];
  const float* enc_Wh  = (const float*)d_in[6];
  const float* enc_bi  = (const float*)d_in[7];
  const float* enc_bh  = (const float*)d_in[8];
  const float* dec_Wi  = (const float*)d_in[9];
  const float* dec_Wh  = (const float*)d_in[10];
  const float* dec_bi  = (const float*)d_in[11];
  const float* dec_bh  = (const float*)d_in[12];
  const float* s2s_Wq  = (const float*)d_in[13];
  const float* s2s_Wk  = (const float*)d_in[14];
  const float* s2s_v   = (const float*)d_in[15];
  const float* W_out   = (const float*)d_in[16];
  const float* b_out   = (const float*)d_in[17];
  const float* ptr_Wq  = (const float*)d_in[18];
  const float* ptr_Wk  = (const float*)d_in[19];
  const float* ptr_v   = (const float*)d_in[20];

  float* ws = (float*)d_ws;
  float* logits = (float*)d_out;
  float* preds  = (float*)d_out + 128 * 64 * 64;

  k_init2<<<256, 256, 0, stream>>>(ws + OFF_HA, (int*)(ws + OFF_SMASK),
                                   (unsigned*)(ws + OFF_SLOTS),
                                   (unsigned*)(ws + OFF_FLG));
  k_persist<<<256, 512, 0, stream>>>(inputs, lengths, targets, W_in, b_in,
                                     enc_Wi, enc_Wh, enc_bi, enc_bh,
                                     dec_Wi, dec_Wh, dec_bi, dec_bh,
                                     s2s_Wq, s2s_Wk, s2s_v, W_out, b_out,
                                     ptr_Wq, ptr_Wk, ptr_v,
                                     ws, logits, preds);
}